// Round 1
// baseline (8266.819 us; speedup 1.0000x reference)
//
#include <hip/hip_runtime.h>
#include <math.h>

// Problem constants
constexpr int D     = 1024;
constexpr int NH    = 16;
constexpr int HD    = 64;
constexpr int SEQ   = 2048;
constexpr int BATCH = 4;
constexpr int NTOK  = BATCH * SEQ;   // 8192 rows

// ---------------------------------------------------------------------------
// Reductions (wave = 64 on CDNA)
// ---------------------------------------------------------------------------
__device__ __forceinline__ float block_reduce_sum(float v, float* red) {
    int lane = threadIdx.x & 63, wid = threadIdx.x >> 6;
    #pragma unroll
    for (int off = 32; off > 0; off >>= 1) v += __shfl_down(v, off, 64);
    if (lane == 0) red[wid] = v;
    __syncthreads();
    float r = red[0] + red[1] + red[2] + red[3];
    __syncthreads();
    return r;
}

__device__ __forceinline__ float block_reduce_max(float v, float* red) {
    int lane = threadIdx.x & 63, wid = threadIdx.x >> 6;
    #pragma unroll
    for (int off = 32; off > 0; off >>= 1) v = fmaxf(v, __shfl_down(v, off, 64));
    if (lane == 0) red[wid] = v;
    __syncthreads();
    float r = fmaxf(fmaxf(red[0], red[1]), fmaxf(red[2], red[3]));
    __syncthreads();
    return r;
}

// ---------------------------------------------------------------------------
// 1) LayerNorm: one 256-thread block per row of 1024
// ---------------------------------------------------------------------------
__global__ __launch_bounds__(256) void ln_kernel(const float* __restrict__ x,
                                                 const float* __restrict__ w,
                                                 const float* __restrict__ b,
                                                 float* __restrict__ h) {
    __shared__ float red[4];
    int row = blockIdx.x;
    const float* xr = x + (size_t)row * D;
    int t = threadIdx.x;
    float v[4];
    float s = 0.f;
    #pragma unroll
    for (int i = 0; i < 4; i++) { v[i] = xr[t + 256 * i]; s += v[i]; }
    float mean = block_reduce_sum(s, red) * (1.0f / 1024.0f);
    float ss = 0.f;
    #pragma unroll
    for (int i = 0; i < 4; i++) { float d = v[i] - mean; ss += d * d; }
    float var = block_reduce_sum(ss, red) * (1.0f / 1024.0f);
    float rstd = rsqrtf(var + 1e-5f);
    float* hr = h + (size_t)row * D;
    #pragma unroll
    for (int i = 0; i < 4; i++) {
        int c = t + 256 * i;
        hr[c] = (v[i] - mean) * rstd * w[c] + b[c];
    }
}

// ---------------------------------------------------------------------------
// 2) fp32 GEMM: C[M,N] = A[M,K] @ B[N,K]^T + bias[N] (+ R[M,N] residual)
//    64x64 block tile, 16 K-tile, 256 threads, 4x4 per thread.
//    M,N multiples of 64, K multiple of 16 (true here: 8192 / 3072,1024 / 1024)
// ---------------------------------------------------------------------------
template <bool RES>
__global__ __launch_bounds__(256) void gemm_kernel(const float* __restrict__ A,
                                                   const float* __restrict__ Bm,
                                                   const float* __restrict__ bias,
                                                   const float* __restrict__ R,
                                                   float* __restrict__ C,
                                                   int M, int N, int K) {
    __shared__ float As[64][17];
    __shared__ float Bs[64][17];
    int tid = threadIdx.x;
    int m0 = (tid >> 4) * 4;
    int n0 = (tid & 15) * 4;
    int rowBase = blockIdx.y * 64;
    int colBase = blockIdx.x * 64;
    int lr = tid >> 2;        // 0..63: row within tile for the staging load
    int lk = (tid & 3) * 4;   // k offset (float4)

    float acc[4][4] = {};

    for (int k0 = 0; k0 < K; k0 += 16) {
        float4 av = *reinterpret_cast<const float4*>(&A[(size_t)(rowBase + lr) * K + k0 + lk]);
        float4 bv = *reinterpret_cast<const float4*>(&Bm[(size_t)(colBase + lr) * K + k0 + lk]);
        As[lr][lk + 0] = av.x; As[lr][lk + 1] = av.y; As[lr][lk + 2] = av.z; As[lr][lk + 3] = av.w;
        Bs[lr][lk + 0] = bv.x; Bs[lr][lk + 1] = bv.y; Bs[lr][lk + 2] = bv.z; Bs[lr][lk + 3] = bv.w;
        __syncthreads();
        #pragma unroll
        for (int kk = 0; kk < 16; kk++) {
            float a[4], bb[4];
            #pragma unroll
            for (int i = 0; i < 4; i++) a[i] = As[m0 + i][kk];
            #pragma unroll
            for (int j = 0; j < 4; j++) bb[j] = Bs[n0 + j][kk];
            #pragma unroll
            for (int i = 0; i < 4; i++)
                #pragma unroll
                for (int j = 0; j < 4; j++)
                    acc[i][j] = fmaf(a[i], bb[j], acc[i][j]);
        }
        __syncthreads();
    }

    #pragma unroll
    for (int i = 0; i < 4; i++) {
        int gm = rowBase + m0 + i;
        #pragma unroll
        for (int j = 0; j < 4; j++) {
            int gn = colBase + n0 + j;
            float val = acc[i][j] + bias[gn];
            if (RES) val += R[(size_t)gm * N + gn];
            C[(size_t)gm * N + gn] = val;
        }
    }
}

// ---------------------------------------------------------------------------
// 3) q/k L2 normalization in-place: one wave per (token,head)
//    qkv layout: [8192][3072], q cols [0,1024), k cols [1024,2048)
// ---------------------------------------------------------------------------
__global__ __launch_bounds__(256) void qknorm_kernel(float* __restrict__ qkv) {
    int gw = (blockIdx.x * 256 + threadIdx.x) >> 6;  // global wave id
    int lane = threadIdx.x & 63;
    if (gw >= NTOK * NH) return;
    int row = gw / NH, hh = gw - row * NH;
    float* qp = qkv + (size_t)row * 3072 + hh * 64;
    float* kp = qp + 1024;

    float qv = qp[lane];
    float s = qv * qv;
    #pragma unroll
    for (int off = 32; off > 0; off >>= 1) s += __shfl_down(s, off, 64);
    s = __shfl(s, 0, 64);
    qp[lane] = qv / fmaxf(sqrtf(s), 1e-12f);

    float kv = kp[lane];
    float s2 = kv * kv;
    #pragma unroll
    for (int off = 32; off > 0; off >>= 1) s2 += __shfl_down(s2, off, 64);
    s2 = __shfl(s2, 0, 64);
    kp[lane] = kv / fmaxf(sqrtf(s2), 1e-12f);
}

// ---------------------------------------------------------------------------
// 4) Attention: one 256-thread block handles 4 query rows of one (b,h).
//    Two-pass softmax with scores in LDS (4 x 2048 fp32 = 32 KB).
//    out[row][h*64+d] = softmax(q.K^T * 8) @ V
// ---------------------------------------------------------------------------
__global__ __launch_bounds__(256) void attn_kernel(const float* __restrict__ qkv,
                                                   float* __restrict__ out) {
    __shared__ float qs[4][64];
    __shared__ float sc[4][SEQ];
    __shared__ float red[4];
    __shared__ float rsum[4];
    __shared__ float pv[4][4][64];  // [group][row][d]

    constexpr int NQT = SEQ / 4;           // 512 q-tiles per (b,h)
    int bh = blockIdx.x / NQT;
    int qt = blockIdx.x - bh * NQT;
    int b = bh / NH, hh = bh - b * NH;
    int tid = threadIdx.x;
    size_t rowq0 = (size_t)b * SEQ + qt * 4;

    // load 4 normalized q rows
    {
        int r = tid >> 6, d = tid & 63;
        qs[r][d] = qkv[(rowq0 + r) * 3072 + hh * 64 + d];
    }
    __syncthreads();

    // scores: each thread computes 8 keys x 4 rows
    for (int j = tid; j < SEQ; j += 256) {
        const float* kr = qkv + ((size_t)b * SEQ + j) * 3072 + 1024 + hh * 64;
        float dot[4] = {0.f, 0.f, 0.f, 0.f};
        #pragma unroll
        for (int d4 = 0; d4 < 16; d4++) {
            float4 kq = reinterpret_cast<const float4*>(kr)[d4];
            #pragma unroll
            for (int r = 0; r < 4; r++) {
                dot[r] += kq.x * qs[r][d4 * 4 + 0] + kq.y * qs[r][d4 * 4 + 1] +
                          kq.z * qs[r][d4 * 4 + 2] + kq.w * qs[r][d4 * 4 + 3];
            }
        }
        #pragma unroll
        for (int r = 0; r < 4; r++) sc[r][j] = dot[r] * 8.0f;
    }
    __syncthreads();

    // softmax per row (two-pass, uniform control flow)
    for (int r = 0; r < 4; r++) {
        float m = -1e30f;
        for (int j = tid; j < SEQ; j += 256) m = fmaxf(m, sc[r][j]);
        m = block_reduce_max(m, red);
        float s = 0.f;
        for (int j = tid; j < SEQ; j += 256) {
            float p = __expf(sc[r][j] - m);
            sc[r][j] = p;
            s += p;
        }
        s = block_reduce_sum(s, red);
        if (tid == 0) rsum[r] = s;
    }
    __syncthreads();

    // PV: thread (g,d): partial over j in [g*512, g*512+512)
    int d = tid & 63, g = tid >> 6;
    float acc[4] = {0.f, 0.f, 0.f, 0.f};
    const float* vbase = qkv + (size_t)b * SEQ * 3072 + 2048 + hh * 64 + d;
    for (int j = g * 512; j < g * 512 + 512; j++) {
        float vv = vbase[(size_t)j * 3072];
        #pragma unroll
        for (int r = 0; r < 4; r++) acc[r] += sc[r][j] * vv;
    }
    #pragma unroll
    for (int r = 0; r < 4; r++) pv[g][r][d] = acc[r];
    __syncthreads();
    if (g == 0) {
        #pragma unroll
        for (int r = 0; r < 4; r++) {
            float t = pv[0][r][d] + pv[1][r][d] + pv[2][r][d] + pv[3][r][d];
            out[(rowq0 + r) * (size_t)D + hh * 64 + d] = t / rsum[r];
        }
    }
}

// ---------------------------------------------------------------------------
// launch
// ---------------------------------------------------------------------------
extern "C" void kernel_launch(void* const* d_in, const int* in_sizes, int n_in,
                              void* d_out, int out_size, void* d_ws, size_t ws_size,
                              hipStream_t stream) {
    const float* x     = (const float*)d_in[0];
    const float* ln_w  = (const float*)d_in[1];
    const float* ln_b  = (const float*)d_in[2];
    const float* qkv_w = (const float*)d_in[3];
    const float* qkv_b = (const float*)d_in[4];
    const float* out_w = (const float*)d_in[5];
    const float* out_b = (const float*)d_in[6];
    float* y = (float*)d_out;

    // workspace: h [8192,1024] (reused as attn_out), qkv [8192,3072] => 128 MB
    float* h   = (float*)d_ws;
    float* qkv = h + (size_t)NTOK * D;
    float* attn_out = h;  // reuse after QKV GEMM consumed h

    // 1) LayerNorm
    ln_kernel<<<NTOK, 256, 0, stream>>>(x, ln_w, ln_b, h);

    // 2) QKV GEMM: [8192,1024] @ [3072,1024]^T
    {
        dim3 grid(3 * D / 64, NTOK / 64);
        gemm_kernel<false><<<grid, 256, 0, stream>>>(h, qkv_w, qkv_b, nullptr, qkv,
                                                     NTOK, 3 * D, D);
    }

    // 3) q/k L2 normalize in place
    {
        int waves = NTOK * NH;             // 131072
        qknorm_kernel<<<waves / 4, 256, 0, stream>>>(qkv);
    }

    // 4) attention
    {
        int blocks = BATCH * NH * (SEQ / 4);  // 32768
        attn_kernel<<<blocks, 256, 0, stream>>>(qkv, attn_out);
    }

    // 5) out projection + residual: y = x + attn_out @ out_w^T + out_b
    {
        dim3 grid(D / 64, NTOK / 64);
        gemm_kernel<true><<<grid, 256, 0, stream>>>(attn_out, out_w, out_b, x, y,
                                                    NTOK, D, D);
    }
}

// Round 2
// 1662.510 us; speedup vs baseline: 4.9725x; 4.9725x over previous
//
#include <hip/hip_runtime.h>
#include <math.h>

// Problem constants
constexpr int D     = 1024;
constexpr int NH    = 16;
constexpr int HD    = 64;
constexpr int SEQ   = 2048;
constexpr int BATCH = 4;
constexpr int NTOK  = BATCH * SEQ;   // 8192 rows

// MFMA fragment types (per guide §3: short-based bf16 frags, compile-verified on gfx950)
typedef short s16x8 __attribute__((ext_vector_type(8)));
typedef short s16x4 __attribute__((ext_vector_type(4)));
typedef float f32x4 __attribute__((ext_vector_type(4)));

__device__ __forceinline__ short f2bf(float f) {
    unsigned u = __float_as_uint(f);
    unsigned r = (u + 0x7FFFu + ((u >> 16) & 1u)) >> 16;   // RNE truncate
    return (short)r;
}
__device__ __forceinline__ float bf2f(short s) {
    return __uint_as_float(((unsigned)(unsigned short)s) << 16);
}

// ---------------------------------------------------------------------------
// Reductions (wave = 64 on CDNA)
// ---------------------------------------------------------------------------
__device__ __forceinline__ float block_reduce_sum(float v, float* red) {
    int lane = threadIdx.x & 63, wid = threadIdx.x >> 6;
    #pragma unroll
    for (int off = 32; off > 0; off >>= 1) v += __shfl_down(v, off, 64);
    if (lane == 0) red[wid] = v;
    __syncthreads();
    float r = red[0] + red[1] + red[2] + red[3];
    __syncthreads();
    return r;
}

// ---------------------------------------------------------------------------
// 1) LayerNorm: one 256-thread block per row of 1024
// ---------------------------------------------------------------------------
__global__ __launch_bounds__(256) void ln_kernel(const float* __restrict__ x,
                                                 const float* __restrict__ w,
                                                 const float* __restrict__ b,
                                                 float* __restrict__ h) {
    __shared__ float red[4];
    int row = blockIdx.x;
    const float* xr = x + (size_t)row * D;
    int t = threadIdx.x;
    float v[4];
    float s = 0.f;
    #pragma unroll
    for (int i = 0; i < 4; i++) { v[i] = xr[t + 256 * i]; s += v[i]; }
    float mean = block_reduce_sum(s, red) * (1.0f / 1024.0f);
    float ss = 0.f;
    #pragma unroll
    for (int i = 0; i < 4; i++) { float d = v[i] - mean; ss += d * d; }
    float var = block_reduce_sum(ss, red) * (1.0f / 1024.0f);
    float rstd = rsqrtf(var + 1e-5f);
    float* hr = h + (size_t)row * D;
    #pragma unroll
    for (int i = 0; i < 4; i++) {
        int c = t + 256 * i;
        hr[c] = (v[i] - mean) * rstd * w[c] + b[c];
    }
}

// ---------------------------------------------------------------------------
// 2) fp32 GEMM: C[M,N] = A[M,K] @ B[N,K]^T + bias[N] (+ R[M,N] residual)
// ---------------------------------------------------------------------------
template <bool RES>
__global__ __launch_bounds__(256) void gemm_kernel(const float* __restrict__ A,
                                                   const float* __restrict__ Bm,
                                                   const float* __restrict__ bias,
                                                   const float* __restrict__ R,
                                                   float* __restrict__ C,
                                                   int M, int N, int K) {
    __shared__ float As[64][17];
    __shared__ float Bs[64][17];
    int tid = threadIdx.x;
    int m0 = (tid >> 4) * 4;
    int n0 = (tid & 15) * 4;
    int rowBase = blockIdx.y * 64;
    int colBase = blockIdx.x * 64;
    int lr = tid >> 2;
    int lk = (tid & 3) * 4;

    float acc[4][4] = {};

    for (int k0 = 0; k0 < K; k0 += 16) {
        float4 av = *reinterpret_cast<const float4*>(&A[(size_t)(rowBase + lr) * K + k0 + lk]);
        float4 bv = *reinterpret_cast<const float4*>(&Bm[(size_t)(colBase + lr) * K + k0 + lk]);
        As[lr][lk + 0] = av.x; As[lr][lk + 1] = av.y; As[lr][lk + 2] = av.z; As[lr][lk + 3] = av.w;
        Bs[lr][lk + 0] = bv.x; Bs[lr][lk + 1] = bv.y; Bs[lr][lk + 2] = bv.z; Bs[lr][lk + 3] = bv.w;
        __syncthreads();
        #pragma unroll
        for (int kk = 0; kk < 16; kk++) {
            float a[4], bb[4];
            #pragma unroll
            for (int i = 0; i < 4; i++) a[i] = As[m0 + i][kk];
            #pragma unroll
            for (int j = 0; j < 4; j++) bb[j] = Bs[n0 + j][kk];
            #pragma unroll
            for (int i = 0; i < 4; i++)
                #pragma unroll
                for (int j = 0; j < 4; j++)
                    acc[i][j] = fmaf(a[i], bb[j], acc[i][j]);
        }
        __syncthreads();
    }

    #pragma unroll
    for (int i = 0; i < 4; i++) {
        int gm = rowBase + m0 + i;
        #pragma unroll
        for (int j = 0; j < 4; j++) {
            int gn = colBase + n0 + j;
            float val = acc[i][j] + bias[gn];
            if (RES) val += R[(size_t)gm * N + gn];
            C[(size_t)gm * N + gn] = val;
        }
    }
}

// ---------------------------------------------------------------------------
// 3) q/k L2 normalization in-place: one wave per (token,head)
// ---------------------------------------------------------------------------
__global__ __launch_bounds__(256) void qknorm_kernel(float* __restrict__ qkv) {
    int gw = (blockIdx.x * 256 + threadIdx.x) >> 6;
    int lane = threadIdx.x & 63;
    if (gw >= NTOK * NH) return;
    int row = gw / NH, hh = gw - row * NH;
    float* qp = qkv + (size_t)row * 3072 + hh * 64;
    float* kp = qp + 1024;

    float qv = qp[lane];
    float s = qv * qv;
    #pragma unroll
    for (int off = 32; off > 0; off >>= 1) s += __shfl_down(s, off, 64);
    s = __shfl(s, 0, 64);
    qp[lane] = qv / fmaxf(sqrtf(s), 1e-12f);

    float kv = kp[lane];
    float s2 = kv * kv;
    #pragma unroll
    for (int off = 32; off > 0; off >>= 1) s2 += __shfl_down(s2, off, 64);
    s2 = __shfl(s2, 0, 64);
    kp[lane] = kv / fmaxf(sqrtf(s2), 1e-12f);
}

// ---------------------------------------------------------------------------
// 4) MFMA flash attention.
//    Block = one (b,h) x 64 q-rows; 4 waves x 16 q-rows; loop over 32
//    key-blocks of 64 keys. Since q,k are L2-normalized, |score| <= 8
//    exactly -> fixed-max softmax exp(s-8), no online rescaling.
//    MFMA layouts (guide §3, HW-verified):
//      A[m=lane&15][k=quad*8+j], B[n=lane&15][k=quad*8+j],
//      C/D: col=lane&15, row=quad*4+reg.
// ---------------------------------------------------------------------------
__global__ __launch_bounds__(256) void mha_kernel(const float* __restrict__ qkv,
                                                  float* __restrict__ out) {
    constexpr int LDP = 72;  // padded LDS stride: keeps 16B alignment (72*2=144B),
                             // breaks 16-way bank aliasing -> 2-way (free)
    __shared__ short Ks[64][LDP];      // K tile  [key][hd]
    __shared__ short Vt[64][LDP];      // V tile  [hd][key]  (transposed)
    __shared__ short Ps[4][16][LDP];   // per-wave P [qrow][key]

    int bh = blockIdx.x >> 5;          // SEQ/64 = 32 q-tiles
    int qt = blockIdx.x & 31;
    int b  = bh >> 4, h = bh & 15;     // NH = 16
    int tid = threadIdx.x;
    int wave = tid >> 6, lane = tid & 63;
    int quad = lane >> 4, l16 = lane & 15;

    const size_t rs = 3072;  // qkv row stride (floats)

    // --- Q A-frags (2 k-halves), loaded once ---
    const float* qbase = qkv + ((size_t)(b * SEQ) + qt * 64 + wave * 16 + l16) * rs + h * 64;
    s16x8 aq[2];
    #pragma unroll
    for (int hh = 0; hh < 2; hh++) {
        const float* qp = qbase + hh * 32 + quad * 8;
        float4 f0 = *(const float4*)(qp);
        float4 f1 = *(const float4*)(qp + 4);
        aq[hh][0] = f2bf(f0.x); aq[hh][1] = f2bf(f0.y); aq[hh][2] = f2bf(f0.z); aq[hh][3] = f2bf(f0.w);
        aq[hh][4] = f2bf(f1.x); aq[hh][5] = f2bf(f1.y); aq[hh][6] = f2bf(f1.z); aq[hh][7] = f2bf(f1.w);
    }

    f32x4 zero = {0.f, 0.f, 0.f, 0.f};
    f32x4 o[4] = {zero, zero, zero, zero};
    float lsum[4] = {0.f, 0.f, 0.f, 0.f};

    // staging assignments
    int skey = tid >> 2, sseg = tid & 3;   // K: thread covers [skey][sseg*16..+15]
    int vkey = tid & 63, vhg  = tid >> 6;  // V: thread covers [vkey][vhg*16..+15] -> transposed
    const float* kglob = qkv + ((size_t)(b * SEQ) + skey) * rs + 1024 + h * 64 + sseg * 16;
    const float* vglob = qkv + ((size_t)(b * SEQ) + vkey) * rs + 2048 + h * 64 + vhg * 16;

    for (int kb = 0; kb < SEQ / 64; kb++) {
        __syncthreads();   // previous iteration's LDS reads done before overwrite
        {
            const float* kp = kglob + (size_t)kb * 64 * rs;
            #pragma unroll
            for (int i = 0; i < 4; i++) {
                float4 f = *(const float4*)(kp + 4 * i);
                s16x4 w4; w4[0] = f2bf(f.x); w4[1] = f2bf(f.y); w4[2] = f2bf(f.z); w4[3] = f2bf(f.w);
                *(s16x4*)&Ks[skey][sseg * 16 + 4 * i] = w4;
            }
            const float* vp = vglob + (size_t)kb * 64 * rs;
            #pragma unroll
            for (int i = 0; i < 4; i++) {
                float4 f = *(const float4*)(vp + 4 * i);
                Vt[vhg * 16 + 4 * i + 0][vkey] = f2bf(f.x);
                Vt[vhg * 16 + 4 * i + 1][vkey] = f2bf(f.y);
                Vt[vhg * 16 + 4 * i + 2][vkey] = f2bf(f.z);
                Vt[vhg * 16 + 4 * i + 3][vkey] = f2bf(f.w);
            }
        }
        __syncthreads();

        // --- S = Q.K^T over 4 key sub-tiles; p = exp(8*s - 8) ---
        float p[4][4];
        #pragma unroll
        for (int t = 0; t < 4; t++) {
            f32x4 s = zero;
            s16x8 b0 = *(const s16x8*)&Ks[t * 16 + l16][quad * 8];
            s16x8 b1 = *(const s16x8*)&Ks[t * 16 + l16][32 + quad * 8];
            s = __builtin_amdgcn_mfma_f32_16x16x32_bf16(aq[0], b0, s, 0, 0, 0);
            s = __builtin_amdgcn_mfma_f32_16x16x32_bf16(aq[1], b1, s, 0, 0, 0);
            #pragma unroll
            for (int r = 0; r < 4; r++) p[t][r] = __expf(s[r] * 8.0f - 8.0f);
        }

        // --- P -> LDS (bf16, A-layout source), row-sums from rounded values ---
        #pragma unroll
        for (int t = 0; t < 4; t++) {
            #pragma unroll
            for (int r = 0; r < 4; r++) {
                short pb = f2bf(p[t][r]);
                Ps[wave][quad * 4 + r][t * 16 + l16] = pb;
                p[t][r] = bf2f(pb);
            }
        }
        #pragma unroll
        for (int r = 0; r < 4; r++) {
            float t0 = p[0][r] + p[1][r] + p[2][r] + p[3][r];
            #pragma unroll
            for (int off = 1; off < 16; off <<= 1) t0 += __shfl_xor(t0, off, 64);
            lsum[r] += t0;   // row quad*4+r, replicated across the quad's 16 lanes
        }

        // --- O += P.V ---
        s16x8 a0 = *(const s16x8*)&Ps[wave][l16][quad * 8];
        s16x8 a1 = *(const s16x8*)&Ps[wave][l16][32 + quad * 8];
        #pragma unroll
        for (int ht = 0; ht < 4; ht++) {
            s16x8 v0 = *(const s16x8*)&Vt[ht * 16 + l16][quad * 8];
            s16x8 v1 = *(const s16x8*)&Vt[ht * 16 + l16][32 + quad * 8];
            o[ht] = __builtin_amdgcn_mfma_f32_16x16x32_bf16(a0, v0, o[ht], 0, 0, 0);
            o[ht] = __builtin_amdgcn_mfma_f32_16x16x32_bf16(a1, v1, o[ht], 0, 0, 0);
        }
    }

    // --- epilogue: divide by row sum, store ---
    int qrow = b * SEQ + qt * 64 + wave * 16 + quad * 4;
    #pragma unroll
    for (int r = 0; r < 4; r++) {
        float inv = 1.0f / lsum[r];
        #pragma unroll
        for (int ht = 0; ht < 4; ht++) {
            out[(size_t)(qrow + r) * D + h * 64 + ht * 16 + l16] = o[ht][r] * inv;
        }
    }
}

// ---------------------------------------------------------------------------
// launch
// ---------------------------------------------------------------------------
extern "C" void kernel_launch(void* const* d_in, const int* in_sizes, int n_in,
                              void* d_out, int out_size, void* d_ws, size_t ws_size,
                              hipStream_t stream) {
    const float* x     = (const float*)d_in[0];
    const float* ln_w  = (const float*)d_in[1];
    const float* ln_b  = (const float*)d_in[2];
    const float* qkv_w = (const float*)d_in[3];
    const float* qkv_b = (const float*)d_in[4];
    const float* out_w = (const float*)d_in[5];
    const float* out_b = (const float*)d_in[6];
    float* y = (float*)d_out;

    float* h   = (float*)d_ws;
    float* qkv = h + (size_t)NTOK * D;
    float* attn_out = h;  // reuse h after QKV GEMM consumed it

    // 1) LayerNorm
    ln_kernel<<<NTOK, 256, 0, stream>>>(x, ln_w, ln_b, h);

    // 2) QKV GEMM: [8192,1024] @ [3072,1024]^T
    {
        dim3 grid(3 * D / 64, NTOK / 64);
        gemm_kernel<false><<<grid, 256, 0, stream>>>(h, qkv_w, qkv_b, nullptr, qkv,
                                                     NTOK, 3 * D, D);
    }

    // 3) q/k L2 normalize in place
    qknorm_kernel<<<NTOK * NH / 4, 256, 0, stream>>>(qkv);

    // 4) MFMA flash attention
    {
        int blocks = BATCH * NH * (SEQ / 64);  // 2048
        mha_kernel<<<blocks, 256, 0, stream>>>(qkv, attn_out);
    }

    // 5) out projection + residual
    {
        dim3 grid(D / 64, NTOK / 64);
        gemm_kernel<true><<<grid, 256, 0, stream>>>(attn_out, out_w, out_b, x, y,
                                                    NTOK, D, D);
    }
}

// Round 3
// 428.425 us; speedup vs baseline: 19.2958x; 3.8805x over previous
//
#include <hip/hip_runtime.h>
#include <math.h>

// Problem constants
constexpr int D     = 1024;
constexpr int NH    = 16;
constexpr int HD    = 64;
constexpr int SEQ   = 2048;
constexpr int BATCH = 4;
constexpr int NTOK  = BATCH * SEQ;   // 8192 rows

typedef short s16x8 __attribute__((ext_vector_type(8)));
typedef short s16x4 __attribute__((ext_vector_type(4)));
typedef float f32x4 __attribute__((ext_vector_type(4)));
typedef unsigned short u16;

__device__ __forceinline__ short f2bf(float f) {
    unsigned u = __float_as_uint(f);
    unsigned r = (u + 0x7FFFu + ((u >> 16) & 1u)) >> 16;   // RNE
    return (short)r;
}
__device__ __forceinline__ float bf2f(u16 s) {
    return __uint_as_float(((unsigned)s) << 16);
}

__device__ __forceinline__ void async_lds16(const void* g, void* l) {
    __builtin_amdgcn_global_load_lds(
        (const __attribute__((address_space(1))) unsigned int*)g,
        (__attribute__((address_space(3))) unsigned int*)l, 16, 0, 0);
}

// ---------------------------------------------------------------------------
// Reductions (wave = 64)
// ---------------------------------------------------------------------------
__device__ __forceinline__ float block_reduce_sum(float v, float* red) {
    int lane = threadIdx.x & 63, wid = threadIdx.x >> 6;
    #pragma unroll
    for (int off = 32; off > 0; off >>= 1) v += __shfl_down(v, off, 64);
    if (lane == 0) red[wid] = v;
    __syncthreads();
    float r = red[0] + red[1] + red[2] + red[3];
    __syncthreads();
    return r;
}

// ---------------------------------------------------------------------------
// 1) LayerNorm (fp32 math) -> bf16 h
// ---------------------------------------------------------------------------
__global__ __launch_bounds__(256) void ln_kernel(const float* __restrict__ x,
                                                 const float* __restrict__ w,
                                                 const float* __restrict__ b,
                                                 u16* __restrict__ h) {
    __shared__ float red[4];
    int row = blockIdx.x;
    const float* xr = x + (size_t)row * D;
    int t = threadIdx.x;
    float v[4];
    float s = 0.f;
    #pragma unroll
    for (int i = 0; i < 4; i++) { v[i] = xr[t + 256 * i]; s += v[i]; }
    float mean = block_reduce_sum(s, red) * (1.0f / 1024.0f);
    float ss = 0.f;
    #pragma unroll
    for (int i = 0; i < 4; i++) { float d = v[i] - mean; ss += d * d; }
    float var = block_reduce_sum(ss, red) * (1.0f / 1024.0f);
    float rstd = rsqrtf(var + 1e-5f);
    u16* hr = h + (size_t)row * D;
    #pragma unroll
    for (int i = 0; i < 4; i++) {
        int c = t + 256 * i;
        hr[c] = (u16)f2bf((v[i] - mean) * rstd * w[c] + b[c]);
    }
}

// ---------------------------------------------------------------------------
// 1b) fp32 -> bf16 cast (weights); n divisible by 1024
// ---------------------------------------------------------------------------
__global__ __launch_bounds__(256) void cast_kernel(const float* __restrict__ in,
                                                   u16* __restrict__ out, int n) {
    int i = (blockIdx.x * 256 + threadIdx.x) * 4;
    if (i >= n) return;
    float4 f = *(const float4*)(in + i);
    s16x4 o4;
    o4[0] = f2bf(f.x); o4[1] = f2bf(f.y); o4[2] = f2bf(f.z); o4[3] = f2bf(f.w);
    *(s16x4*)(out + i) = o4;
}

// ---------------------------------------------------------------------------
// 2) bf16 MFMA GEMM (m97 structure): C[M,N] = A[M,K] @ B[N,K]^T + bias (+R)
//    128x128 tile, BK=32, 256 threads = 4 waves x (64x64), global_load_lds
//    width-16 staging into unpadded [row][32] bf16 LDS (lane order == DMA
//    order: lane l -> row l>>2, k-chunk (l&3)*8).
// ---------------------------------------------------------------------------
template <typename OutT, bool RES>
__global__ __launch_bounds__(256) void gemm_bf16(const u16* __restrict__ A,
                                                 const u16* __restrict__ B,
                                                 const float* __restrict__ bias,
                                                 const float* __restrict__ R,
                                                 OutT* __restrict__ C,
                                                 int M, int N, int K) {
    __shared__ u16 As[128 * 32];
    __shared__ u16 Bs[128 * 32];
    int tid = threadIdx.x, wave = tid >> 6, lane = tid & 63;
    int quad = lane >> 4, l16 = lane & 15;
    int wm = (wave & 1) * 64, wn = (wave >> 1) * 64;
    int rowBase = blockIdx.y * 128, colBase = blockIdx.x * 128;

    int srow = lane >> 2;        // 0..15
    int sk8  = (lane & 3) * 8;   // bf16 offset within 32-wide row

    f32x4 acc[4][4];
    #pragma unroll
    for (int i = 0; i < 4; i++)
        #pragma unroll
        for (int j = 0; j < 4; j++)
            acc[i][j] = (f32x4){0.f, 0.f, 0.f, 0.f};

    for (int k0 = 0; k0 < K; k0 += 32) {
        __syncthreads();
        #pragma unroll
        for (int i = 0; i < 2; i++) {
            int r = wave * 32 + i * 16;   // wave-uniform LDS base row
            const u16* ga = A + (size_t)(rowBase + r + srow) * K + k0 + sk8;
            async_lds16(ga, &As[r * 32]);
            const u16* gb = B + (size_t)(colBase + r + srow) * K + k0 + sk8;
            async_lds16(gb, &Bs[r * 32]);
        }
        __syncthreads();

        s16x8 af[4], bfr[4];
        #pragma unroll
        for (int t = 0; t < 4; t++) {
            af[t]  = *(const s16x8*)&As[(wm + t * 16 + l16) * 32 + quad * 8];
            bfr[t] = *(const s16x8*)&Bs[(wn + t * 16 + l16) * 32 + quad * 8];
        }
        #pragma unroll
        for (int mt = 0; mt < 4; mt++)
            #pragma unroll
            for (int nt = 0; nt < 4; nt++)
                acc[mt][nt] = __builtin_amdgcn_mfma_f32_16x16x32_bf16(
                    af[mt], bfr[nt], acc[mt][nt], 0, 0, 0);
    }

    // epilogue: C/D layout col=lane&15, row=quad*4+reg
    #pragma unroll
    for (int mt = 0; mt < 4; mt++) {
        #pragma unroll
        for (int nt = 0; nt < 4; nt++) {
            int gm0 = rowBase + wm + mt * 16 + quad * 4;
            int gn  = colBase + wn + nt * 16 + l16;
            float bv = bias[gn];
            #pragma unroll
            for (int r = 0; r < 4; r++) {
                int gm = gm0 + r;
                float val = acc[mt][nt][r] + bv;
                if (RES) val += R[(size_t)gm * N + gn];
                if constexpr (sizeof(OutT) == 2)
                    C[(size_t)gm * N + gn] = (OutT)f2bf(val);
                else
                    C[(size_t)gm * N + gn] = val;
            }
        }
    }
}

// ---------------------------------------------------------------------------
// 3) q/k L2 normalization in-place on bf16 qkv
// ---------------------------------------------------------------------------
__global__ __launch_bounds__(256) void qknorm_kernel(u16* __restrict__ qkv) {
    int gw = (blockIdx.x * 256 + threadIdx.x) >> 6;
    int lane = threadIdx.x & 63;
    int row = gw / NH, hh = gw - row * NH;
    u16* qp = qkv + (size_t)row * 3072 + hh * 64;
    u16* kp = qp + 1024;

    float qv = bf2f(qp[lane]);
    float s = qv * qv;
    #pragma unroll
    for (int off = 32; off > 0; off >>= 1) s += __shfl_down(s, off, 64);
    s = __shfl(s, 0, 64);
    qp[lane] = (u16)f2bf(qv / fmaxf(sqrtf(s), 1e-12f));

    float kv = bf2f(kp[lane]);
    float s2 = kv * kv;
    #pragma unroll
    for (int off = 32; off > 0; off >>= 1) s2 += __shfl_down(s2, off, 64);
    s2 = __shfl(s2, 0, 64);
    kp[lane] = (u16)f2bf(kv / fmaxf(sqrtf(s2), 1e-12f));
}

// ---------------------------------------------------------------------------
// 4) MFMA flash attention (bf16 qkv in, bf16 out).
//    Block = one (b,h) x 64 q-rows; 4 waves x 16 q-rows; 32 key-blocks of 64.
//    |score| <= 8 exactly (L2-normalized q,k) -> fixed-max softmax exp(s-8).
// ---------------------------------------------------------------------------
__global__ __launch_bounds__(256) void mha_kernel(const u16* __restrict__ qkv,
                                                  u16* __restrict__ out) {
    constexpr int LDP = 72;  // pad: 144 B row stride, 16B-aligned, 2-way banks
    __shared__ u16 Ks[64][LDP];      // K tile  [key][hd]
    __shared__ u16 Vt[64][LDP];      // V tile  [hd][key] (transposed)
    __shared__ u16 Ps[4][16][LDP];   // per-wave P [qrow][key]

    int bh = blockIdx.x >> 5;
    int qt = blockIdx.x & 31;
    int b  = bh >> 4, h = bh & 15;
    int tid = threadIdx.x;
    int wave = tid >> 6, lane = tid & 63;
    int quad = lane >> 4, l16 = lane & 15;

    const size_t rs = 3072;

    const u16* qbase = qkv + ((size_t)(b * SEQ) + qt * 64 + wave * 16 + l16) * rs + h * 64;
    s16x8 aq[2];
    aq[0] = *(const s16x8*)(qbase + quad * 8);
    aq[1] = *(const s16x8*)(qbase + 32 + quad * 8);

    f32x4 zero = {0.f, 0.f, 0.f, 0.f};
    f32x4 o[4] = {zero, zero, zero, zero};
    float lsum[4] = {0.f, 0.f, 0.f, 0.f};

    int skey = tid >> 2, sseg = tid & 3;   // K: [skey][sseg*16..+15]
    int vkey = tid & 63, vhg  = tid >> 6;  // V: [vkey][vhg*16..+15] -> transposed
    const u16* kglob = qkv + ((size_t)(b * SEQ) + skey) * rs + 1024 + h * 64 + sseg * 16;
    const u16* vglob = qkv + ((size_t)(b * SEQ) + vkey) * rs + 2048 + h * 64 + vhg * 16;

    for (int kb = 0; kb < SEQ / 64; kb++) {
        __syncthreads();
        {
            const u16* kp = kglob + (size_t)kb * 64 * rs;
            *(s16x8*)&Ks[skey][sseg * 16]     = ((const s16x8*)kp)[0];
            *(s16x8*)&Ks[skey][sseg * 16 + 8] = ((const s16x8*)kp)[1];
            const u16* vp = vglob + (size_t)kb * 64 * rs;
            s16x8 v0 = ((const s16x8*)vp)[0];
            s16x8 v1 = ((const s16x8*)vp)[1];
            #pragma unroll
            for (int i = 0; i < 8; i++) Vt[vhg * 16 + i][vkey] = v0[i];
            #pragma unroll
            for (int i = 0; i < 8; i++) Vt[vhg * 16 + 8 + i][vkey] = v1[i];
        }
        __syncthreads();

        // --- S = Q.K^T ; p = exp(8*s - 8) ---
        float p[4][4];
        #pragma unroll
        for (int t = 0; t < 4; t++) {
            f32x4 s = zero;
            s16x8 b0 = *(const s16x8*)&Ks[t * 16 + l16][quad * 8];
            s16x8 b1 = *(const s16x8*)&Ks[t * 16 + l16][32 + quad * 8];
            s = __builtin_amdgcn_mfma_f32_16x16x32_bf16(aq[0], b0, s, 0, 0, 0);
            s = __builtin_amdgcn_mfma_f32_16x16x32_bf16(aq[1], b1, s, 0, 0, 0);
            #pragma unroll
            for (int r = 0; r < 4; r++) p[t][r] = __expf(s[r] * 8.0f - 8.0f);
        }

        // --- P -> LDS (C-layout -> A-layout round-trip), row-sums ---
        #pragma unroll
        for (int t = 0; t < 4; t++) {
            #pragma unroll
            for (int r = 0; r < 4; r++) {
                short pb = f2bf(p[t][r]);
                Ps[wave][quad * 4 + r][t * 16 + l16] = (u16)pb;
                p[t][r] = bf2f((u16)pb);
            }
        }
        #pragma unroll
        for (int r = 0; r < 4; r++) {
            float t0 = p[0][r] + p[1][r] + p[2][r] + p[3][r];
            #pragma unroll
            for (int off = 1; off < 16; off <<= 1) t0 += __shfl_xor(t0, off, 64);
            lsum[r] += t0;
        }

        // --- O += P.V ---
        s16x8 a0 = *(const s16x8*)&Ps[wave][l16][quad * 8];
        s16x8 a1 = *(const s16x8*)&Ps[wave][l16][32 + quad * 8];
        #pragma unroll
        for (int ht = 0; ht < 4; ht++) {
            s16x8 v0 = *(const s16x8*)&Vt[ht * 16 + l16][quad * 8];
            s16x8 v1 = *(const s16x8*)&Vt[ht * 16 + l16][32 + quad * 8];
            o[ht] = __builtin_amdgcn_mfma_f32_16x16x32_bf16(a0, v0, o[ht], 0, 0, 0);
            o[ht] = __builtin_amdgcn_mfma_f32_16x16x32_bf16(a1, v1, o[ht], 0, 0, 0);
        }
    }

    int qrow = b * SEQ + qt * 64 + wave * 16 + quad * 4;
    #pragma unroll
    for (int r = 0; r < 4; r++) {
        float inv = 1.0f / lsum[r];
        #pragma unroll
        for (int ht = 0; ht < 4; ht++) {
            out[(size_t)(qrow + r) * D + h * 64 + ht * 16 + l16] = (u16)f2bf(o[ht][r] * inv);
        }
    }
}

// ---------------------------------------------------------------------------
// launch
// ---------------------------------------------------------------------------
extern "C" void kernel_launch(void* const* d_in, const int* in_sizes, int n_in,
                              void* d_out, int out_size, void* d_ws, size_t ws_size,
                              hipStream_t stream) {
    const float* x     = (const float*)d_in[0];
    const float* ln_w  = (const float*)d_in[1];
    const float* ln_b  = (const float*)d_in[2];
    const float* qkv_w = (const float*)d_in[3];
    const float* qkv_b = (const float*)d_in[4];
    const float* out_w = (const float*)d_in[5];
    const float* out_b = (const float*)d_in[6];
    float* y = (float*)d_out;

    // workspace carve-up (bytes): qkv 48MB | h 16MB | wq 6MB | wo 2MB
    char* ws = (char*)d_ws;
    u16* qkv   = (u16*)ws;                                  // [8192][3072]
    u16* h     = (u16*)(ws + (size_t)48 * 1024 * 1024);     // [8192][1024]
    u16* wq    = (u16*)(ws + (size_t)64 * 1024 * 1024);     // [3072][1024]
    u16* wo    = (u16*)(ws + (size_t)70 * 1024 * 1024);     // [1024][1024]
    u16* attn_out = h;  // h is consumed by GEMM1 before attention writes

    // 1) LayerNorm -> bf16 h ; weight casts
    ln_kernel<<<NTOK, 256, 0, stream>>>(x, ln_w, ln_b, h);
    cast_kernel<<<(3 * D * D) / 1024, 256, 0, stream>>>(qkv_w, wq, 3 * D * D);
    cast_kernel<<<(D * D) / 1024, 256, 0, stream>>>(out_w, wo, D * D);

    // 2) QKV GEMM (bf16 MFMA): [8192,1024] @ [3072,1024]^T -> bf16 qkv
    {
        dim3 grid(3 * D / 128, NTOK / 128);
        gemm_bf16<u16, false><<<grid, 256, 0, stream>>>(h, wq, qkv_b, nullptr, qkv,
                                                        NTOK, 3 * D, D);
    }

    // 3) q/k L2 normalize in place (bf16)
    qknorm_kernel<<<NTOK * NH / 4, 256, 0, stream>>>(qkv);

    // 4) MFMA flash attention -> bf16 attn_out
    mha_kernel<<<BATCH * NH * (SEQ / 64), 256, 0, stream>>>(qkv, attn_out);

    // 5) out projection + residual (bf16 MFMA, fp32 out): y = x + A@Wo^T + b
    {
        dim3 grid(D / 128, NTOK / 128);
        gemm_bf16<float, true><<<grid, 256, 0, stream>>>(attn_out, wo, out_b, x, y,
                                                         NTOK, D, D);
    }
}

// Round 4
// 398.888 us; speedup vs baseline: 20.7247x; 1.0740x over previous
//
#include <hip/hip_runtime.h>
#include <math.h>

// Problem constants
constexpr int D     = 1024;
constexpr int NH    = 16;
constexpr int HD    = 64;
constexpr int SEQ   = 2048;
constexpr int BATCH = 4;
constexpr int NTOK  = BATCH * SEQ;   // 8192 rows

typedef short s16x8 __attribute__((ext_vector_type(8)));
typedef short s16x4 __attribute__((ext_vector_type(4)));
typedef float f32x4 __attribute__((ext_vector_type(4)));
typedef unsigned short u16;
typedef unsigned int   u32;

__device__ __forceinline__ short f2bf(float f) {
    unsigned u = __float_as_uint(f);
    unsigned r = (u + 0x7FFFu + ((u >> 16) & 1u)) >> 16;   // RNE
    return (short)r;
}
__device__ __forceinline__ float bf2f(u16 s) {
    return __uint_as_float(((unsigned)s) << 16);
}

__device__ __forceinline__ void async_lds16(const void* g, void* l) {
    __builtin_amdgcn_global_load_lds(
        (const __attribute__((address_space(1))) unsigned int*)g,
        (__attribute__((address_space(3))) unsigned int*)l, 16, 0, 0);
}

// ---------------------------------------------------------------------------
// Reductions (wave = 64)
// ---------------------------------------------------------------------------
__device__ __forceinline__ float block_reduce_sum(float v, float* red) {
    int lane = threadIdx.x & 63, wid = threadIdx.x >> 6;
    #pragma unroll
    for (int off = 32; off > 0; off >>= 1) v += __shfl_down(v, off, 64);
    if (lane == 0) red[wid] = v;
    __syncthreads();
    float r = red[0] + red[1] + red[2] + red[3];
    __syncthreads();
    return r;
}

// ---------------------------------------------------------------------------
// 1) LayerNorm (fp32 math) -> bf16 h
// ---------------------------------------------------------------------------
__global__ __launch_bounds__(256) void ln_kernel(const float* __restrict__ x,
                                                 const float* __restrict__ w,
                                                 const float* __restrict__ b,
                                                 u16* __restrict__ h) {
    __shared__ float red[4];
    int row = blockIdx.x;
    const float* xr = x + (size_t)row * D;
    int t = threadIdx.x;
    float v[4];
    float s = 0.f;
    #pragma unroll
    for (int i = 0; i < 4; i++) { v[i] = xr[t + 256 * i]; s += v[i]; }
    float mean = block_reduce_sum(s, red) * (1.0f / 1024.0f);
    float ss = 0.f;
    #pragma unroll
    for (int i = 0; i < 4; i++) { float d = v[i] - mean; ss += d * d; }
    float var = block_reduce_sum(ss, red) * (1.0f / 1024.0f);
    float rstd = rsqrtf(var + 1e-5f);
    u16* hr = h + (size_t)row * D;
    #pragma unroll
    for (int i = 0; i < 4; i++) {
        int c = t + 256 * i;
        hr[c] = (u16)f2bf((v[i] - mean) * rstd * w[c] + b[c]);
    }
}

// ---------------------------------------------------------------------------
// 1b) fp32 -> bf16 cast (weights); n divisible by 1024
// ---------------------------------------------------------------------------
__global__ __launch_bounds__(256) void cast_kernel(const float* __restrict__ in,
                                                   u16* __restrict__ out, int n) {
    int i = (blockIdx.x * 256 + threadIdx.x) * 4;
    if (i >= n) return;
    float4 f = *(const float4*)(in + i);
    s16x4 o4;
    o4[0] = f2bf(f.x); o4[1] = f2bf(f.y); o4[2] = f2bf(f.z); o4[3] = f2bf(f.w);
    *(s16x4*)(out + i) = o4;
}

// ---------------------------------------------------------------------------
// 2) bf16 MFMA GEMM (m97 structure): C[M,N] = A[M,K] @ B[N,K]^T + bias (+R)
// ---------------------------------------------------------------------------
template <typename OutT, bool RES>
__global__ __launch_bounds__(256) void gemm_bf16(const u16* __restrict__ A,
                                                 const u16* __restrict__ B,
                                                 const float* __restrict__ bias,
                                                 const float* __restrict__ R,
                                                 OutT* __restrict__ C,
                                                 int M, int N, int K) {
    __shared__ u16 As[128 * 32];
    __shared__ u16 Bs[128 * 32];
    int tid = threadIdx.x, wave = tid >> 6, lane = tid & 63;
    int quad = lane >> 4, l16 = lane & 15;
    int wm = (wave & 1) * 64, wn = (wave >> 1) * 64;
    int rowBase = blockIdx.y * 128, colBase = blockIdx.x * 128;

    int srow = lane >> 2;
    int sk8  = (lane & 3) * 8;

    f32x4 acc[4][4];
    #pragma unroll
    for (int i = 0; i < 4; i++)
        #pragma unroll
        for (int j = 0; j < 4; j++)
            acc[i][j] = (f32x4){0.f, 0.f, 0.f, 0.f};

    for (int k0 = 0; k0 < K; k0 += 32) {
        __syncthreads();
        #pragma unroll
        for (int i = 0; i < 2; i++) {
            int r = wave * 32 + i * 16;
            const u16* ga = A + (size_t)(rowBase + r + srow) * K + k0 + sk8;
            async_lds16(ga, &As[r * 32]);
            const u16* gb = B + (size_t)(colBase + r + srow) * K + k0 + sk8;
            async_lds16(gb, &Bs[r * 32]);
        }
        __syncthreads();

        s16x8 af[4], bfr[4];
        #pragma unroll
        for (int t = 0; t < 4; t++) {
            af[t]  = *(const s16x8*)&As[(wm + t * 16 + l16) * 32 + quad * 8];
            bfr[t] = *(const s16x8*)&Bs[(wn + t * 16 + l16) * 32 + quad * 8];
        }
        #pragma unroll
        for (int mt = 0; mt < 4; mt++)
            #pragma unroll
            for (int nt = 0; nt < 4; nt++)
                acc[mt][nt] = __builtin_amdgcn_mfma_f32_16x16x32_bf16(
                    af[mt], bfr[nt], acc[mt][nt], 0, 0, 0);
    }

    #pragma unroll
    for (int mt = 0; mt < 4; mt++) {
        #pragma unroll
        for (int nt = 0; nt < 4; nt++) {
            int gm0 = rowBase + wm + mt * 16 + quad * 4;
            int gn  = colBase + wn + nt * 16 + l16;
            float bv = bias[gn];
            #pragma unroll
            for (int r = 0; r < 4; r++) {
                int gm = gm0 + r;
                float val = acc[mt][nt][r] + bv;
                if (RES) val += R[(size_t)gm * N + gn];
                if constexpr (sizeof(OutT) == 2)
                    C[(size_t)gm * N + gn] = (OutT)f2bf(val);
                else
                    C[(size_t)gm * N + gn] = val;
            }
        }
    }
}

// ---------------------------------------------------------------------------
// 3) q/k L2 normalization in-place on bf16 qkv
// ---------------------------------------------------------------------------
__global__ __launch_bounds__(256) void qknorm_kernel(u16* __restrict__ qkv) {
    int gw = (blockIdx.x * 256 + threadIdx.x) >> 6;
    int lane = threadIdx.x & 63;
    int row = gw / NH, hh = gw - row * NH;
    u16* qp = qkv + (size_t)row * 3072 + hh * 64;
    u16* kp = qp + 1024;

    float qv = bf2f(qp[lane]);
    float s = qv * qv;
    #pragma unroll
    for (int off = 32; off > 0; off >>= 1) s += __shfl_down(s, off, 64);
    s = __shfl(s, 0, 64);
    qp[lane] = (u16)f2bf(qv / fmaxf(sqrtf(s), 1e-12f));

    float kv = bf2f(kp[lane]);
    float s2 = kv * kv;
    #pragma unroll
    for (int off = 32; off > 0; off >>= 1) s2 += __shfl_down(s2, off, 64);
    s2 = __shfl(s2, 0, 64);
    kp[lane] = (u16)f2bf(kv / fmaxf(sqrtf(s2), 1e-12f));
}

// ---------------------------------------------------------------------------
// 4) MFMA flash attention v2.
//    Block = one (b,h) x 128 q-rows; 4 waves x 32 q-rows (2 row-tiles of 16);
//    32 key-blocks of 64 keys, software-prefetched into regs one tile ahead.
//    |score| <= 8 exactly -> fixed-max softmax exp(8s-8).
// ---------------------------------------------------------------------------
__global__ __launch_bounds__(256) void mha_kernel(const u16* __restrict__ qkv,
                                                  u16* __restrict__ out) {
    constexpr int LDP = 72;  // u16 row stride: 144 B, 16B-aligned, 2-way banks
    __shared__ u16 Ks[64][LDP];       // K tile  [key][hd]
    __shared__ u16 Vt[64][LDP];       // V tile  [hd][key] (transposed)
    __shared__ u16 Ps[4][32][LDP];    // per-wave P [qrow 0..31][key]

    int bh = blockIdx.x >> 4;         // SEQ/128 = 16 q-tiles
    int qt = blockIdx.x & 15;
    int b  = bh >> 4, h = bh & 15;
    int tid = threadIdx.x;
    int wave = tid >> 6, lane = tid & 63;
    int quad = lane >> 4, l16 = lane & 15;

    const size_t rs = 3072;

    // --- Q A-frags: 2 row-tiles x 2 k-halves ---
    s16x8 aq[2][2];
    #pragma unroll
    for (int rt = 0; rt < 2; rt++) {
        const u16* qb = qkv + ((size_t)(b * SEQ) + qt * 128 + wave * 32 + rt * 16 + l16) * rs + h * 64;
        aq[rt][0] = *(const s16x8*)(qb + quad * 8);
        aq[rt][1] = *(const s16x8*)(qb + 32 + quad * 8);
    }

    f32x4 zero = {0.f, 0.f, 0.f, 0.f};
    f32x4 o[2][4];
    #pragma unroll
    for (int rt = 0; rt < 2; rt++)
        #pragma unroll
        for (int ht = 0; ht < 4; ht++) o[rt][ht] = zero;
    float lsum[2][4] = {};

    // staging assignments
    int skey = tid >> 2, sseg = (tid & 3) * 16;   // K: [skey][sseg..sseg+15]
    int p2 = tid >> 3, dc = (tid & 7) * 8;        // V: key pair (2p2,2p2+1), d dc..dc+7
    const u16* kglob  = qkv + ((size_t)(b * SEQ) + skey) * rs + 1024 + h * 64 + sseg;
    const u16* vglob0 = qkv + ((size_t)(b * SEQ) + 2 * p2) * rs + 2048 + h * 64 + dc;
    u32* vt32 = (u32*)&Vt[0][0];

    // prefetch tile 0
    s16x8 kr0 = ((const s16x8*)kglob)[0];
    s16x8 kr1 = ((const s16x8*)kglob)[1];
    s16x8 vr0 = *(const s16x8*)(vglob0);
    s16x8 vr1 = *(const s16x8*)(vglob0 + rs);

    for (int kb = 0; kb < SEQ / 64; kb++) {
        __syncthreads();   // previous tile's LDS reads done
        // write prefetched tile to LDS
        *(s16x8*)&Ks[skey][sseg]     = kr0;
        *(s16x8*)&Ks[skey][sseg + 8] = kr1;
        #pragma unroll
        for (int i = 0; i < 8; i++) {
            u32 pk = (u32)(u16)vr0[i] | ((u32)(u16)vr1[i] << 16);
            vt32[(dc + i) * (LDP / 2) + p2] = pk;
        }
        __syncthreads();

        // prefetch next tile into regs (overlaps with compute below)
        if (kb < SEQ / 64 - 1) {
            const u16* kp = kglob + (size_t)(kb + 1) * 64 * rs;
            const u16* vp = vglob0 + (size_t)(kb + 1) * 64 * rs;
            kr0 = ((const s16x8*)kp)[0];
            kr1 = ((const s16x8*)kp)[1];
            vr0 = *(const s16x8*)(vp);
            vr1 = *(const s16x8*)(vp + rs);
        }

        // K frags hoisted (reused by both row-tiles)
        s16x8 bk[4][2];
        #pragma unroll
        for (int t = 0; t < 4; t++) {
            bk[t][0] = *(const s16x8*)&Ks[t * 16 + l16][quad * 8];
            bk[t][1] = *(const s16x8*)&Ks[t * 16 + l16][32 + quad * 8];
        }

        // --- S = Q.K^T ; p = exp(8s - 8) ; P -> per-wave LDS ---
        #pragma unroll
        for (int rt = 0; rt < 2; rt++) {
            float p[4][4];
            #pragma unroll
            for (int t = 0; t < 4; t++) {
                f32x4 s = zero;
                s = __builtin_amdgcn_mfma_f32_16x16x32_bf16(aq[rt][0], bk[t][0], s, 0, 0, 0);
                s = __builtin_amdgcn_mfma_f32_16x16x32_bf16(aq[rt][1], bk[t][1], s, 0, 0, 0);
                #pragma unroll
                for (int r = 0; r < 4; r++) p[t][r] = __expf(s[r] * 8.0f - 8.0f);
            }
            #pragma unroll
            for (int t = 0; t < 4; t++) {
                #pragma unroll
                for (int r = 0; r < 4; r++) {
                    short pb = f2bf(p[t][r]);
                    Ps[wave][rt * 16 + quad * 4 + r][t * 16 + l16] = (u16)pb;
                    p[t][r] = bf2f((u16)pb);
                }
            }
            #pragma unroll
            for (int r = 0; r < 4; r++) {
                float t0 = p[0][r] + p[1][r] + p[2][r] + p[3][r];
                #pragma unroll
                for (int off = 1; off < 16; off <<= 1) t0 += __shfl_xor(t0, off, 64);
                lsum[rt][r] += t0;
            }
        }

        // V frags hoisted (reused by both row-tiles)
        s16x8 vf[4][2];
        #pragma unroll
        for (int ht = 0; ht < 4; ht++) {
            vf[ht][0] = *(const s16x8*)&Vt[ht * 16 + l16][quad * 8];
            vf[ht][1] = *(const s16x8*)&Vt[ht * 16 + l16][32 + quad * 8];
        }

        // --- O += P.V ---
        #pragma unroll
        for (int rt = 0; rt < 2; rt++) {
            s16x8 a0 = *(const s16x8*)&Ps[wave][rt * 16 + l16][quad * 8];
            s16x8 a1 = *(const s16x8*)&Ps[wave][rt * 16 + l16][32 + quad * 8];
            #pragma unroll
            for (int ht = 0; ht < 4; ht++) {
                o[rt][ht] = __builtin_amdgcn_mfma_f32_16x16x32_bf16(a0, vf[ht][0], o[rt][ht], 0, 0, 0);
                o[rt][ht] = __builtin_amdgcn_mfma_f32_16x16x32_bf16(a1, vf[ht][1], o[rt][ht], 0, 0, 0);
            }
        }
    }

    #pragma unroll
    for (int rt = 0; rt < 2; rt++) {
        int qrow = b * SEQ + qt * 128 + wave * 32 + rt * 16 + quad * 4;
        #pragma unroll
        for (int r = 0; r < 4; r++) {
            float inv = 1.0f / lsum[rt][r];
            #pragma unroll
            for (int ht = 0; ht < 4; ht++) {
                out[(size_t)(qrow + r) * D + h * 64 + ht * 16 + l16] =
                    (u16)f2bf(o[rt][ht][r] * inv);
            }
        }
    }
}

// ---------------------------------------------------------------------------
// launch
// ---------------------------------------------------------------------------
extern "C" void kernel_launch(void* const* d_in, const int* in_sizes, int n_in,
                              void* d_out, int out_size, void* d_ws, size_t ws_size,
                              hipStream_t stream) {
    const float* x     = (const float*)d_in[0];
    const float* ln_w  = (const float*)d_in[1];
    const float* ln_b  = (const float*)d_in[2];
    const float* qkv_w = (const float*)d_in[3];
    const float* qkv_b = (const float*)d_in[4];
    const float* out_w = (const float*)d_in[5];
    const float* out_b = (const float*)d_in[6];
    float* y = (float*)d_out;

    // workspace carve-up: qkv 48MB | h 16MB | wq 6MB | wo 2MB
    char* ws = (char*)d_ws;
    u16* qkv = (u16*)ws;
    u16* h   = (u16*)(ws + (size_t)48 * 1024 * 1024);
    u16* wq  = (u16*)(ws + (size_t)64 * 1024 * 1024);
    u16* wo  = (u16*)(ws + (size_t)70 * 1024 * 1024);
    u16* attn_out = h;

    ln_kernel<<<NTOK, 256, 0, stream>>>(x, ln_w, ln_b, h);
    cast_kernel<<<(3 * D * D) / 1024, 256, 0, stream>>>(qkv_w, wq, 3 * D * D);
    cast_kernel<<<(D * D) / 1024, 256, 0, stream>>>(out_w, wo, D * D);

    {
        dim3 grid(3 * D / 128, NTOK / 128);
        gemm_bf16<u16, false><<<grid, 256, 0, stream>>>(h, wq, qkv_b, nullptr, qkv,
                                                        NTOK, 3 * D, D);
    }

    qknorm_kernel<<<NTOK * NH / 4, 256, 0, stream>>>(qkv);

    mha_kernel<<<BATCH * NH * (SEQ / 128), 256, 0, stream>>>(qkv, attn_out);

    {
        dim3 grid(D / 128, NTOK / 128);
        gemm_bf16<float, true><<<grid, 256, 0, stream>>>(attn_out, wo, out_b, x, y,
                                                         NTOK, D, D);
    }
}

// Round 5
// 355.282 us; speedup vs baseline: 23.2684x; 1.1227x over previous
//
#include <hip/hip_runtime.h>
#include <math.h>

// Problem constants
constexpr int D     = 1024;
constexpr int NH    = 16;
constexpr int HD    = 64;
constexpr int SEQ   = 2048;
constexpr int BATCH = 4;
constexpr int NTOK  = BATCH * SEQ;   // 8192 rows

typedef short s16x8 __attribute__((ext_vector_type(8)));
typedef short s16x4 __attribute__((ext_vector_type(4)));
typedef float f32x4 __attribute__((ext_vector_type(4)));
typedef unsigned short u16;
typedef unsigned int   u32;

__device__ __forceinline__ short f2bf(float f) {
    unsigned u = __float_as_uint(f);
    unsigned r = (u + 0x7FFFu + ((u >> 16) & 1u)) >> 16;   // RNE
    return (short)r;
}
__device__ __forceinline__ float bf2f(u16 s) {
    return __uint_as_float(((unsigned)s) << 16);
}

// pack hi16(b1)|hi16(b0) -> one u32 (lo = b0) via v_perm_b32
__device__ __forceinline__ u32 pack_bf16_pair(float f0, float f1) {
    u32 a = __float_as_uint(f1) + 0x8000u;   // round half up
    u32 b = __float_as_uint(f0) + 0x8000u;
    return __builtin_amdgcn_perm(a, b, 0x07060302u);
}

__device__ __forceinline__ void async_lds16(const void* g, void* l) {
    __builtin_amdgcn_global_load_lds(
        (const __attribute__((address_space(1))) unsigned int*)g,
        (__attribute__((address_space(3))) unsigned int*)l, 16, 0, 0);
}

// ---------------------------------------------------------------------------
// Reductions (wave = 64)
// ---------------------------------------------------------------------------
__device__ __forceinline__ float block_reduce_sum(float v, float* red) {
    int lane = threadIdx.x & 63, wid = threadIdx.x >> 6;
    #pragma unroll
    for (int off = 32; off > 0; off >>= 1) v += __shfl_down(v, off, 64);
    if (lane == 0) red[wid] = v;
    __syncthreads();
    float r = red[0] + red[1] + red[2] + red[3];
    __syncthreads();
    return r;
}

// ---------------------------------------------------------------------------
// 1) LayerNorm (fp32 math) -> bf16 h
// ---------------------------------------------------------------------------
__global__ __launch_bounds__(256) void ln_kernel(const float* __restrict__ x,
                                                 const float* __restrict__ w,
                                                 const float* __restrict__ b,
                                                 u16* __restrict__ h) {
    __shared__ float red[4];
    int row = blockIdx.x;
    const float* xr = x + (size_t)row * D;
    int t = threadIdx.x;
    float v[4];
    float s = 0.f;
    #pragma unroll
    for (int i = 0; i < 4; i++) { v[i] = xr[t + 256 * i]; s += v[i]; }
    float mean = block_reduce_sum(s, red) * (1.0f / 1024.0f);
    float ss = 0.f;
    #pragma unroll
    for (int i = 0; i < 4; i++) { float d = v[i] - mean; ss += d * d; }
    float var = block_reduce_sum(ss, red) * (1.0f / 1024.0f);
    float rstd = rsqrtf(var + 1e-5f);
    u16* hr = h + (size_t)row * D;
    #pragma unroll
    for (int i = 0; i < 4; i++) {
        int c = t + 256 * i;
        hr[c] = (u16)f2bf((v[i] - mean) * rstd * w[c] + b[c]);
    }
}

// ---------------------------------------------------------------------------
// 1b) fp32 -> bf16 cast (weights); n divisible by 1024
// ---------------------------------------------------------------------------
__global__ __launch_bounds__(256) void cast_kernel(const float* __restrict__ in,
                                                   u16* __restrict__ out, int n) {
    int i = (blockIdx.x * 256 + threadIdx.x) * 4;
    if (i >= n) return;
    float4 f = *(const float4*)(in + i);
    s16x4 o4;
    o4[0] = f2bf(f.x); o4[1] = f2bf(f.y); o4[2] = f2bf(f.z); o4[3] = f2bf(f.w);
    *(s16x4*)(out + i) = o4;
}

// ---------------------------------------------------------------------------
// 2) bf16 MFMA GEMM (m97 structure): C[M,N] = A[M,K] @ B[N,K]^T + bias (+R)
// ---------------------------------------------------------------------------
template <typename OutT, bool RES>
__global__ __launch_bounds__(256) void gemm_bf16(const u16* __restrict__ A,
                                                 const u16* __restrict__ B,
                                                 const float* __restrict__ bias,
                                                 const float* __restrict__ R,
                                                 OutT* __restrict__ C,
                                                 int M, int N, int K) {
    __shared__ u16 As[128 * 32];
    __shared__ u16 Bs[128 * 32];
    int tid = threadIdx.x, wave = tid >> 6, lane = tid & 63;
    int quad = lane >> 4, l16 = lane & 15;
    int wm = (wave & 1) * 64, wn = (wave >> 1) * 64;
    int rowBase = blockIdx.y * 128, colBase = blockIdx.x * 128;

    int srow = lane >> 2;
    int sk8  = (lane & 3) * 8;

    f32x4 acc[4][4];
    #pragma unroll
    for (int i = 0; i < 4; i++)
        #pragma unroll
        for (int j = 0; j < 4; j++)
            acc[i][j] = (f32x4){0.f, 0.f, 0.f, 0.f};

    for (int k0 = 0; k0 < K; k0 += 32) {
        __syncthreads();
        #pragma unroll
        for (int i = 0; i < 2; i++) {
            int r = wave * 32 + i * 16;
            const u16* ga = A + (size_t)(rowBase + r + srow) * K + k0 + sk8;
            async_lds16(ga, &As[r * 32]);
            const u16* gb = B + (size_t)(colBase + r + srow) * K + k0 + sk8;
            async_lds16(gb, &Bs[r * 32]);
        }
        __syncthreads();

        s16x8 af[4], bfr[4];
        #pragma unroll
        for (int t = 0; t < 4; t++) {
            af[t]  = *(const s16x8*)&As[(wm + t * 16 + l16) * 32 + quad * 8];
            bfr[t] = *(const s16x8*)&Bs[(wn + t * 16 + l16) * 32 + quad * 8];
        }
        #pragma unroll
        for (int mt = 0; mt < 4; mt++)
            #pragma unroll
            for (int nt = 0; nt < 4; nt++)
                acc[mt][nt] = __builtin_amdgcn_mfma_f32_16x16x32_bf16(
                    af[mt], bfr[nt], acc[mt][nt], 0, 0, 0);
    }

    #pragma unroll
    for (int mt = 0; mt < 4; mt++) {
        #pragma unroll
        for (int nt = 0; nt < 4; nt++) {
            int gm0 = rowBase + wm + mt * 16 + quad * 4;
            int gn  = colBase + wn + nt * 16 + l16;
            float bv = bias[gn];
            #pragma unroll
            for (int r = 0; r < 4; r++) {
                int gm = gm0 + r;
                float val = acc[mt][nt][r] + bv;
                if (RES) val += R[(size_t)gm * N + gn];
                if constexpr (sizeof(OutT) == 2)
                    C[(size_t)gm * N + gn] = (OutT)f2bf(val);
                else
                    C[(size_t)gm * N + gn] = val;
            }
        }
    }
}

// ---------------------------------------------------------------------------
// 3) q/k L2 normalization in-place on bf16 qkv
// ---------------------------------------------------------------------------
__global__ __launch_bounds__(256) void qknorm_kernel(u16* __restrict__ qkv) {
    int gw = (blockIdx.x * 256 + threadIdx.x) >> 6;
    int lane = threadIdx.x & 63;
    int row = gw / NH, hh = gw - row * NH;
    u16* qp = qkv + (size_t)row * 3072 + hh * 64;
    u16* kp = qp + 1024;

    float qv = bf2f(qp[lane]);
    float s = qv * qv;
    #pragma unroll
    for (int off = 32; off > 0; off >>= 1) s += __shfl_down(s, off, 64);
    s = __shfl(s, 0, 64);
    qp[lane] = (u16)f2bf(qv / fmaxf(sqrtf(s), 1e-12f));

    float kv = bf2f(kp[lane]);
    float s2 = kv * kv;
    #pragma unroll
    for (int off = 32; off > 0; off >>= 1) s2 += __shfl_down(s2, off, 64);
    s2 = __shfl(s2, 0, 64);
    kp[lane] = (u16)f2bf(kv / fmaxf(sqrtf(s2), 1e-12f));
}

// ---------------------------------------------------------------------------
// 4) MFMA flash attention v3 — transposed-S dataflow.
//    Block = one (b,h) x 128 q-rows; 4 waves x 32 q-rows (2 row-tiles of 16).
//    S^T = mfma(K_frag, Q_frag) -> C-layout row=key, col=qrow=l16:
//      * P[qrow][key] pairs are contiguous -> v_perm pack + ds_write_b32
//      * row sums are in-lane (15 adds + 2 shfl_xor)
//      * PV as O^T = mfma(Vt_frag, P_Bfrag) -> one divide/rt, dwordx2 stores
//    |score| <= 8 exactly -> fixed-max softmax exp(8s-8).
// ---------------------------------------------------------------------------
__global__ __launch_bounds__(256) void mha_kernel(const u16* __restrict__ qkv,
                                                  u16* __restrict__ out) {
    constexpr int LDP = 72;  // u16 row stride: 144 B, 16B-aligned, spreads banks
    __shared__ u16 Ks[64][LDP];       // K tile  [key][hd]
    __shared__ u16 Vt[64][LDP];       // V tile  [hd][key] (transposed)
    __shared__ u16 Ps[4][32][LDP];    // per-wave P [qrow 0..31][key]

    int bh = blockIdx.x >> 4;         // SEQ/128 = 16 q-tiles
    int qt = blockIdx.x & 15;
    int b  = bh >> 4, h = bh & 15;
    int tid = threadIdx.x;
    int wave = tid >> 6, lane = tid & 63;
    int quad = lane >> 4, l16 = lane & 15;

    const size_t rs = 3072;

    // --- Q frags (used as MFMA B-operand: B[n=qrow][k=d]) ---
    s16x8 aq[2][2];
    #pragma unroll
    for (int rt = 0; rt < 2; rt++) {
        const u16* qb = qkv + ((size_t)(b * SEQ) + qt * 128 + wave * 32 + rt * 16 + l16) * rs + h * 64;
        aq[rt][0] = *(const s16x8*)(qb + quad * 8);
        aq[rt][1] = *(const s16x8*)(qb + 32 + quad * 8);
    }

    f32x4 zero = {0.f, 0.f, 0.f, 0.f};
    f32x4 o2[2][4];   // O^T frags: [rt][ht], lane holds d=ht*16+quad*4+r, qrow=l16
    #pragma unroll
    for (int rt = 0; rt < 2; rt++)
        #pragma unroll
        for (int ht = 0; ht < 4; ht++) o2[rt][ht] = zero;
    float lsum[2] = {0.f, 0.f};   // per-lane qrow = l16 (per rt)

    // staging assignments
    int skey = tid >> 2, sseg = (tid & 3) * 16;   // K: [skey][sseg..sseg+15]
    int p2 = tid >> 3, dc = (tid & 7) * 8;        // V: key pair (2p2,2p2+1), d dc..dc+7
    const u16* kglob  = qkv + ((size_t)(b * SEQ) + skey) * rs + 1024 + h * 64 + sseg;
    const u16* vglob0 = qkv + ((size_t)(b * SEQ) + 2 * p2) * rs + 2048 + h * 64 + dc;
    u32* vt32 = (u32*)&Vt[0][0];

    // prefetch tile 0
    s16x8 kr0 = ((const s16x8*)kglob)[0];
    s16x8 kr1 = ((const s16x8*)kglob)[1];
    s16x8 vr0 = *(const s16x8*)(vglob0);
    s16x8 vr1 = *(const s16x8*)(vglob0 + rs);

    for (int kb = 0; kb < SEQ / 64; kb++) {
        __syncthreads();   // previous tile's LDS reads done
        *(s16x8*)&Ks[skey][sseg]     = kr0;
        *(s16x8*)&Ks[skey][sseg + 8] = kr1;
        #pragma unroll
        for (int i = 0; i < 8; i++) {
            u32 pk = (u32)(u16)vr0[i] | ((u32)(u16)vr1[i] << 16);
            vt32[(dc + i) * (LDP / 2) + p2] = pk;
        }
        __syncthreads();

        // prefetch next tile into regs (overlaps compute)
        if (kb < SEQ / 64 - 1) {
            const u16* kp = kglob + (size_t)(kb + 1) * 64 * rs;
            const u16* vp = vglob0 + (size_t)(kb + 1) * 64 * rs;
            kr0 = ((const s16x8*)kp)[0];
            kr1 = ((const s16x8*)kp)[1];
            vr0 = *(const s16x8*)(vp);
            vr1 = *(const s16x8*)(vp + rs);
        }

        // K frags (A-operand: A[m=key][k=d]); reused by both row-tiles
        s16x8 bk[4][2];
        #pragma unroll
        for (int t = 0; t < 4; t++) {
            bk[t][0] = *(const s16x8*)&Ks[t * 16 + l16][quad * 8];
            bk[t][1] = *(const s16x8*)&Ks[t * 16 + l16][32 + quad * 8];
        }

        // --- S^T = K.Q^T ; p = exp(8s-8) ; pack pairs -> Ps[qrow][key] ---
        #pragma unroll
        for (int rt = 0; rt < 2; rt++) {
            float sum16 = 0.f;
            u32* prow = (u32*)&Ps[wave][rt * 16 + l16][0];
            #pragma unroll
            for (int t = 0; t < 4; t++) {
                f32x4 s = zero;
                s = __builtin_amdgcn_mfma_f32_16x16x32_bf16(bk[t][0], aq[rt][0], s, 0, 0, 0);
                s = __builtin_amdgcn_mfma_f32_16x16x32_bf16(bk[t][1], aq[rt][1], s, 0, 0, 0);
                float p0 = __expf(fmaf(s[0], 8.0f, -8.0f));
                float p1 = __expf(fmaf(s[1], 8.0f, -8.0f));
                float p2_ = __expf(fmaf(s[2], 8.0f, -8.0f));
                float p3 = __expf(fmaf(s[3], 8.0f, -8.0f));
                sum16 += (p0 + p1) + (p2_ + p3);
                // keys t*16+quad*4+{0,1} and {2,3} are u32-contiguous in Ps row
                prow[t * 8 + quad * 2 + 0] = pack_bf16_pair(p0, p1);
                prow[t * 8 + quad * 2 + 1] = pack_bf16_pair(p2_, p3);
            }
            // in-lane row sum: this lane covered 16 keys of qrow=l16;
            // quads cover disjoint keys -> reduce across quads (same l16)
            sum16 += __shfl_xor(sum16, 16, 64);
            sum16 += __shfl_xor(sum16, 32, 64);
            lsum[rt] += sum16;
        }

        // V frags (A-operand: A[m=d][k=key]); reused by both row-tiles
        s16x8 vf[4][2];
        #pragma unroll
        for (int ht = 0; ht < 4; ht++) {
            vf[ht][0] = *(const s16x8*)&Vt[ht * 16 + l16][quad * 8];
            vf[ht][1] = *(const s16x8*)&Vt[ht * 16 + l16][32 + quad * 8];
        }

        // --- O^T += V^T.P^T : B-operand = P[qrow=l16][key] ---
        #pragma unroll
        for (int rt = 0; rt < 2; rt++) {
            s16x8 bp0 = *(const s16x8*)&Ps[wave][rt * 16 + l16][quad * 8];
            s16x8 bp1 = *(const s16x8*)&Ps[wave][rt * 16 + l16][32 + quad * 8];
            #pragma unroll
            for (int ht = 0; ht < 4; ht++) {
                o2[rt][ht] = __builtin_amdgcn_mfma_f32_16x16x32_bf16(vf[ht][0], bp0, o2[rt][ht], 0, 0, 0);
                o2[rt][ht] = __builtin_amdgcn_mfma_f32_16x16x32_bf16(vf[ht][1], bp1, o2[rt][ht], 0, 0, 0);
            }
        }
    }

    // --- epilogue: lane owns qrow=l16 (per rt), d = ht*16+quad*4+r ---
    #pragma unroll
    for (int rt = 0; rt < 2; rt++) {
        float inv = 1.0f / lsum[rt];
        int orow = b * SEQ + qt * 128 + wave * 32 + rt * 16 + l16;
        u16* op = out + (size_t)orow * D + h * 64 + quad * 4;
        #pragma unroll
        for (int ht = 0; ht < 4; ht++) {
            f32x4 v = o2[rt][ht];
            u32 lo = pack_bf16_pair(v[0] * inv, v[1] * inv);
            u32 hi = pack_bf16_pair(v[2] * inv, v[3] * inv);
            uint2 pk = {lo, hi};
            *(uint2*)(op + ht * 16) = pk;
        }
    }
}

// ---------------------------------------------------------------------------
// launch
// ---------------------------------------------------------------------------
extern "C" void kernel_launch(void* const* d_in, const int* in_sizes, int n_in,
                              void* d_out, int out_size, void* d_ws, size_t ws_size,
                              hipStream_t stream) {
    const float* x     = (const float*)d_in[0];
    const float* ln_w  = (const float*)d_in[1];
    const float* ln_b  = (const float*)d_in[2];
    const float* qkv_w = (const float*)d_in[3];
    const float* qkv_b = (const float*)d_in[4];
    const float* out_w = (const float*)d_in[5];
    const float* out_b = (const float*)d_in[6];
    float* y = (float*)d_out;

    // workspace carve-up: qkv 48MB | h 16MB | wq 6MB | wo 2MB
    char* ws = (char*)d_ws;
    u16* qkv = (u16*)ws;
    u16* h   = (u16*)(ws + (size_t)48 * 1024 * 1024);
    u16* wq  = (u16*)(ws + (size_t)64 * 1024 * 1024);
    u16* wo  = (u16*)(ws + (size_t)70 * 1024 * 1024);
    u16* attn_out = h;

    ln_kernel<<<NTOK, 256, 0, stream>>>(x, ln_w, ln_b, h);
    cast_kernel<<<(3 * D * D) / 1024, 256, 0, stream>>>(qkv_w, wq, 3 * D * D);
    cast_kernel<<<(D * D) / 1024, 256, 0, stream>>>(out_w, wo, D * D);

    {
        dim3 grid(3 * D / 128, NTOK / 128);
        gemm_bf16<u16, false><<<grid, 256, 0, stream>>>(h, wq, qkv_b, nullptr, qkv,
                                                        NTOK, 3 * D, D);
    }

    qknorm_kernel<<<NTOK * NH / 4, 256, 0, stream>>>(qkv);

    mha_kernel<<<BATCH * NH * (SEQ / 128), 256, 0, stream>>>(qkv, attn_out);

    {
        dim3 grid(D / 128, NTOK / 128);
        gemm_bf16<float, true><<<grid, 256, 0, stream>>>(attn_out, wo, out_b, x, y,
                                                         NTOK, D, D);
    }
}

// Round 6
// 340.137 us; speedup vs baseline: 24.3044x; 1.0445x over previous
//
#include <hip/hip_runtime.h>
#include <math.h>

// Problem constants
constexpr int D     = 1024;
constexpr int NH    = 16;
constexpr int HD    = 64;
constexpr int SEQ   = 2048;
constexpr int BATCH = 4;
constexpr int NTOK  = BATCH * SEQ;   // 8192 rows

typedef short s16x8 __attribute__((ext_vector_type(8)));
typedef short s16x4 __attribute__((ext_vector_type(4)));
typedef float f32x4 __attribute__((ext_vector_type(4)));
typedef unsigned short u16;
typedef unsigned int   u32;

#if __has_builtin(__builtin_amdgcn_exp2f)
#define EXP2(x) __builtin_amdgcn_exp2f(x)
#else
#define EXP2(x) exp2f(x)
#endif

__device__ __forceinline__ short f2bf(float f) {
    unsigned u = __float_as_uint(f);
    unsigned r = (u + 0x7FFFu + ((u >> 16) & 1u)) >> 16;   // RNE
    return (short)r;
}
__device__ __forceinline__ float bf2f(u16 s) {
    return __uint_as_float(((unsigned)s) << 16);
}

// pack hi16(f1)|hi16(f0) -> one u32 (lo = f0) via v_perm_b32
__device__ __forceinline__ u32 pack_bf16_pair(float f0, float f1) {
    u32 a = __float_as_uint(f1) + 0x8000u;   // round half up
    u32 b = __float_as_uint(f0) + 0x8000u;
    return __builtin_amdgcn_perm(a, b, 0x07060302u);
}

__device__ __forceinline__ void async_lds16(const void* g, void* l) {
    __builtin_amdgcn_global_load_lds(
        (const __attribute__((address_space(1))) unsigned int*)g,
        (__attribute__((address_space(3))) unsigned int*)l, 16, 0, 0);
}

// ---------------------------------------------------------------------------
// Reductions (wave = 64)
// ---------------------------------------------------------------------------
__device__ __forceinline__ float block_reduce_sum(float v, float* red) {
    int lane = threadIdx.x & 63, wid = threadIdx.x >> 6;
    #pragma unroll
    for (int off = 32; off > 0; off >>= 1) v += __shfl_down(v, off, 64);
    if (lane == 0) red[wid] = v;
    __syncthreads();
    float r = red[0] + red[1] + red[2] + red[3];
    __syncthreads();
    return r;
}

// ---------------------------------------------------------------------------
// 1) LayerNorm (fp32 math) -> bf16 h
// ---------------------------------------------------------------------------
__global__ __launch_bounds__(256) void ln_kernel(const float* __restrict__ x,
                                                 const float* __restrict__ w,
                                                 const float* __restrict__ b,
                                                 u16* __restrict__ h) {
    __shared__ float red[4];
    int row = blockIdx.x;
    const float* xr = x + (size_t)row * D;
    int t = threadIdx.x;
    float v[4];
    float s = 0.f;
    #pragma unroll
    for (int i = 0; i < 4; i++) { v[i] = xr[t + 256 * i]; s += v[i]; }
    float mean = block_reduce_sum(s, red) * (1.0f / 1024.0f);
    float ss = 0.f;
    #pragma unroll
    for (int i = 0; i < 4; i++) { float d = v[i] - mean; ss += d * d; }
    float var = block_reduce_sum(ss, red) * (1.0f / 1024.0f);
    float rstd = rsqrtf(var + 1e-5f);
    u16* hr = h + (size_t)row * D;
    #pragma unroll
    for (int i = 0; i < 4; i++) {
        int c = t + 256 * i;
        hr[c] = (u16)f2bf((v[i] - mean) * rstd * w[c] + b[c]);
    }
}

// ---------------------------------------------------------------------------
// 1b) fp32 -> bf16 cast (weights); n divisible by 1024
// ---------------------------------------------------------------------------
__global__ __launch_bounds__(256) void cast_kernel(const float* __restrict__ in,
                                                   u16* __restrict__ out, int n) {
    int i = (blockIdx.x * 256 + threadIdx.x) * 4;
    if (i >= n) return;
    float4 f = *(const float4*)(in + i);
    s16x4 o4;
    o4[0] = f2bf(f.x); o4[1] = f2bf(f.y); o4[2] = f2bf(f.z); o4[3] = f2bf(f.w);
    *(s16x4*)(out + i) = o4;
}

// ---------------------------------------------------------------------------
// 2) bf16 MFMA GEMM (m97 structure): C[M,N] = A[M,K] @ B[N,K]^T + bias (+R)
// ---------------------------------------------------------------------------
template <typename OutT, bool RES>
__global__ __launch_bounds__(256) void gemm_bf16(const u16* __restrict__ A,
                                                 const u16* __restrict__ B,
                                                 const float* __restrict__ bias,
                                                 const float* __restrict__ R,
                                                 OutT* __restrict__ C,
                                                 int M, int N, int K) {
    __shared__ u16 As[128 * 32];
    __shared__ u16 Bs[128 * 32];
    int tid = threadIdx.x, wave = tid >> 6, lane = tid & 63;
    int quad = lane >> 4, l16 = lane & 15;
    int wm = (wave & 1) * 64, wn = (wave >> 1) * 64;
    int rowBase = blockIdx.y * 128, colBase = blockIdx.x * 128;

    int srow = lane >> 2;
    int sk8  = (lane & 3) * 8;

    f32x4 acc[4][4];
    #pragma unroll
    for (int i = 0; i < 4; i++)
        #pragma unroll
        for (int j = 0; j < 4; j++)
            acc[i][j] = (f32x4){0.f, 0.f, 0.f, 0.f};

    for (int k0 = 0; k0 < K; k0 += 32) {
        __syncthreads();
        #pragma unroll
        for (int i = 0; i < 2; i++) {
            int r = wave * 32 + i * 16;
            const u16* ga = A + (size_t)(rowBase + r + srow) * K + k0 + sk8;
            async_lds16(ga, &As[r * 32]);
            const u16* gb = B + (size_t)(colBase + r + srow) * K + k0 + sk8;
            async_lds16(gb, &Bs[r * 32]);
        }
        __syncthreads();

        s16x8 af[4], bfr[4];
        #pragma unroll
        for (int t = 0; t < 4; t++) {
            af[t]  = *(const s16x8*)&As[(wm + t * 16 + l16) * 32 + quad * 8];
            bfr[t] = *(const s16x8*)&Bs[(wn + t * 16 + l16) * 32 + quad * 8];
        }
        #pragma unroll
        for (int mt = 0; mt < 4; mt++)
            #pragma unroll
            for (int nt = 0; nt < 4; nt++)
                acc[mt][nt] = __builtin_amdgcn_mfma_f32_16x16x32_bf16(
                    af[mt], bfr[nt], acc[mt][nt], 0, 0, 0);
    }

    #pragma unroll
    for (int mt = 0; mt < 4; mt++) {
        #pragma unroll
        for (int nt = 0; nt < 4; nt++) {
            int gm0 = rowBase + wm + mt * 16 + quad * 4;
            int gn  = colBase + wn + nt * 16 + l16;
            float bv = bias[gn];
            #pragma unroll
            for (int r = 0; r < 4; r++) {
                int gm = gm0 + r;
                float val = acc[mt][nt][r] + bv;
                if (RES) val += R[(size_t)gm * N + gn];
                if constexpr (sizeof(OutT) == 2)
                    C[(size_t)gm * N + gn] = (OutT)f2bf(val);
                else
                    C[(size_t)gm * N + gn] = val;
            }
        }
    }
}

// ---------------------------------------------------------------------------
// 3) k L2 normalization in-place on bf16 qkv (q is normalized inside mha)
// ---------------------------------------------------------------------------
__global__ __launch_bounds__(256) void knorm_kernel(u16* __restrict__ qkv) {
    int gw = (blockIdx.x * 256 + threadIdx.x) >> 6;
    int lane = threadIdx.x & 63;
    int row = gw / NH, hh = gw - row * NH;
    u16* kp = qkv + (size_t)row * 3072 + 1024 + hh * 64;

    float kv = bf2f(kp[lane]);
    float s = kv * kv;
    #pragma unroll
    for (int off = 32; off > 0; off >>= 1) s += __shfl_down(s, off, 64);
    s = __shfl(s, 0, 64);
    kp[lane] = (u16)f2bf(kv / fmaxf(sqrtf(s), 1e-12f));
}

// ---------------------------------------------------------------------------
// 4) MFMA flash attention v4 — transposed-S, register-resident P.
//    Block = one (b,h) x 128 q-rows; 4 waves x 32 q-rows (2 row-tiles of 16).
//    * S^T = mfma(K, Q*SCL, C=-SCL) -> p = exp2(s) raw (|q.k| <= 1 exactly,
//      SCL = 8*log2e; scale folded into q once per block, bias into C-init).
//    * q L2-norm fused into the once-per-block q load (2 shfl_xor).
//    * PV uses contraction-index permutation: the packed exp'd C-frag IS a
//      valid 16x16x32 B-operand for key order sigma(quad*8+j) =
//      t_pair*16+quad*4+(j&3); matching V A-frags are two ds_read_b64 from
//      the transposed Vt rows. No P LDS round-trip at all.
// ---------------------------------------------------------------------------
__global__ __launch_bounds__(256) void mha_kernel(const u16* __restrict__ qkv,
                                                  u16* __restrict__ out) {
    constexpr int LDP = 72;  // u16 row stride: 144 B, 16B-aligned, spreads banks
    __shared__ u16 Ks[64][LDP];       // K tile  [key][hd]
    __shared__ u16 Vt[64][LDP];       // V tile  [hd][key] (transposed)

    int bh = blockIdx.x >> 4;         // SEQ/128 = 16 q-tiles
    int qt = blockIdx.x & 15;
    int b  = bh >> 4, h = bh & 15;
    int tid = threadIdx.x;
    int wave = tid >> 6, lane = tid & 63;
    int quad = lane >> 4, l16 = lane & 15;

    const size_t rs = 3072;
    constexpr float SCL = 11.5415605f;   // 8 * log2(e)

    // --- Q frags: load raw q, L2-normalize in-register, fold SCL, pack bf16.
    //     B-operand layout: B[n=qrow=l16][k=d=quad*8+j (+32 for half 1)]
    s16x8 aq[2][2];
    #pragma unroll
    for (int rt = 0; rt < 2; rt++) {
        const u16* qb = qkv + ((size_t)(b * SEQ) + qt * 128 + wave * 32 + rt * 16 + l16) * rs + h * 64;
        s16x8 r0 = *(const s16x8*)(qb + quad * 8);
        s16x8 r1 = *(const s16x8*)(qb + 32 + quad * 8);
        float f0[8], f1[8], ss = 0.f;
        #pragma unroll
        for (int i = 0; i < 8; i++) { f0[i] = bf2f((u16)r0[i]); ss = fmaf(f0[i], f0[i], ss); }
        #pragma unroll
        for (int i = 0; i < 8; i++) { f1[i] = bf2f((u16)r1[i]); ss = fmaf(f1[i], f1[i], ss); }
        // quads hold disjoint d-chunks of the same qrow=l16 -> reduce across quads
        ss += __shfl_xor(ss, 16, 64);
        ss += __shfl_xor(ss, 32, 64);
        float inv = SCL / fmaxf(sqrtf(ss), 1e-12f);
        #pragma unroll
        for (int i = 0; i < 8; i++) {
            aq[rt][0][i] = f2bf(f0[i] * inv);
            aq[rt][1][i] = f2bf(f1[i] * inv);
        }
    }

    const f32x4 cinit = {-SCL, -SCL, -SCL, -SCL};
    f32x4 o2[2][4];   // O^T frags: lane holds d=ht*16+quad*4+r, qrow=l16
    #pragma unroll
    for (int rt = 0; rt < 2; rt++)
        #pragma unroll
        for (int ht = 0; ht < 4; ht++) o2[rt][ht] = (f32x4){0.f, 0.f, 0.f, 0.f};
    float lsum[2] = {0.f, 0.f};

    // staging assignments
    int skey = tid >> 2, sseg = (tid & 3) * 16;   // K: [skey][sseg..sseg+15]
    int vp2 = tid >> 3, dc = (tid & 7) * 8;       // V: key pair (2vp2,2vp2+1), d dc..dc+7
    const u16* kglob  = qkv + ((size_t)(b * SEQ) + skey) * rs + 1024 + h * 64 + sseg;
    const u16* vglob0 = qkv + ((size_t)(b * SEQ) + 2 * vp2) * rs + 2048 + h * 64 + dc;
    u32* vt32 = (u32*)&Vt[0][0];

    // prefetch tile 0
    s16x8 kr0 = ((const s16x8*)kglob)[0];
    s16x8 kr1 = ((const s16x8*)kglob)[1];
    s16x8 vr0 = *(const s16x8*)(vglob0);
    s16x8 vr1 = *(const s16x8*)(vglob0 + rs);

    for (int kb = 0; kb < SEQ / 64; kb++) {
        __syncthreads();   // previous tile's LDS reads done
        *(s16x8*)&Ks[skey][sseg]     = kr0;
        *(s16x8*)&Ks[skey][sseg + 8] = kr1;
        #pragma unroll
        for (int i = 0; i < 8; i++) {
            u32 pk = (u32)(u16)vr0[i] | ((u32)(u16)vr1[i] << 16);
            vt32[(dc + i) * (LDP / 2) + vp2] = pk;
        }
        __syncthreads();

        // prefetch next tile into regs (overlaps compute)
        if (kb < SEQ / 64 - 1) {
            const u16* kp = kglob + (size_t)(kb + 1) * 64 * rs;
            const u16* vp = vglob0 + (size_t)(kb + 1) * 64 * rs;
            kr0 = ((const s16x8*)kp)[0];
            kr1 = ((const s16x8*)kp)[1];
            vr0 = *(const s16x8*)(vp);
            vr1 = *(const s16x8*)(vp + rs);
        }

        // K A-frags (A[m=key][k=d]); reused by both row-tiles
        s16x8 bk[4][2];
        #pragma unroll
        for (int t = 0; t < 4; t++) {
            bk[t][0] = *(const s16x8*)&Ks[t * 16 + l16][quad * 8];
            bk[t][1] = *(const s16x8*)&Ks[t * 16 + l16][32 + quad * 8];
        }

        // --- S^T = K.(SCL*Q)^T - SCL ; p = exp2(s); keep packed in regs ---
        s16x4 pfr[2][4];   // [rt][t]: P[qrow=l16][key=t*16+quad*4+{0..3}] bf16
        #pragma unroll
        for (int rt = 0; rt < 2; rt++) {
            float sum16 = 0.f;
            #pragma unroll
            for (int t = 0; t < 4; t++) {
                f32x4 s = cinit;
                s = __builtin_amdgcn_mfma_f32_16x16x32_bf16(bk[t][0], aq[rt][0], s, 0, 0, 0);
                s = __builtin_amdgcn_mfma_f32_16x16x32_bf16(bk[t][1], aq[rt][1], s, 0, 0, 0);
                float p0 = EXP2(s[0]);
                float p1 = EXP2(s[1]);
                float p2 = EXP2(s[2]);
                float p3 = EXP2(s[3]);
                sum16 += (p0 + p1) + (p2 + p3);
                uint2 pk2;
                pk2.x = pack_bf16_pair(p0, p1);
                pk2.y = pack_bf16_pair(p2, p3);
                pfr[rt][t] = __builtin_bit_cast(s16x4, pk2);
            }
            sum16 += __shfl_xor(sum16, 16, 64);
            sum16 += __shfl_xor(sum16, 32, 64);
            lsum[rt] += sum16;
        }

        // --- O^T += V^T.P^T with permuted key order (pairs (0,1),(2,3)) ---
        #pragma unroll
        for (int pr = 0; pr < 2; pr++) {
            int tA = pr * 2, tB = pr * 2 + 1;
            #pragma unroll
            for (int ht = 0; ht < 4; ht++) {
                const u16* vrow = &Vt[ht * 16 + l16][0];
                s16x4 va = *(const s16x4*)(vrow + tA * 16 + quad * 4);
                s16x4 vb = *(const s16x4*)(vrow + tB * 16 + quad * 4);
                s16x8 vfr = __builtin_shufflevector(va, vb, 0, 1, 2, 3, 4, 5, 6, 7);
                #pragma unroll
                for (int rt = 0; rt < 2; rt++) {
                    s16x8 bp = __builtin_shufflevector(pfr[rt][tA], pfr[rt][tB],
                                                       0, 1, 2, 3, 4, 5, 6, 7);
                    o2[rt][ht] = __builtin_amdgcn_mfma_f32_16x16x32_bf16(
                        vfr, bp, o2[rt][ht], 0, 0, 0);
                }
            }
        }
    }

    // --- epilogue: lane owns qrow=l16 (per rt), d = ht*16+quad*4+r ---
    #pragma unroll
    for (int rt = 0; rt < 2; rt++) {
        float inv = 1.0f / lsum[rt];
        int orow = b * SEQ + qt * 128 + wave * 32 + rt * 16 + l16;
        u16* op = out + (size_t)orow * D + h * 64 + quad * 4;
        #pragma unroll
        for (int ht = 0; ht < 4; ht++) {
            f32x4 v = o2[rt][ht];
            u32 lo = pack_bf16_pair(v[0] * inv, v[1] * inv);
            u32 hi = pack_bf16_pair(v[2] * inv, v[3] * inv);
            uint2 pk = {lo, hi};
            *(uint2*)(op + ht * 16) = pk;
        }
    }
}

// ---------------------------------------------------------------------------
// launch
// ---------------------------------------------------------------------------
extern "C" void kernel_launch(void* const* d_in, const int* in_sizes, int n_in,
                              void* d_out, int out_size, void* d_ws, size_t ws_size,
                              hipStream_t stream) {
    const float* x     = (const float*)d_in[0];
    const float* ln_w  = (const float*)d_in[1];
    const float* ln_b  = (const float*)d_in[2];
    const float* qkv_w = (const float*)d_in[3];
    const float* qkv_b = (const float*)d_in[4];
    const float* out_w = (const float*)d_in[5];
    const float* out_b = (const float*)d_in[6];
    float* y = (float*)d_out;

    // workspace carve-up: qkv 48MB | h 16MB | wq 6MB | wo 2MB
    char* ws = (char*)d_ws;
    u16* qkv = (u16*)ws;
    u16* h   = (u16*)(ws + (size_t)48 * 1024 * 1024);
    u16* wq  = (u16*)(ws + (size_t)64 * 1024 * 1024);
    u16* wo  = (u16*)(ws + (size_t)70 * 1024 * 1024);
    u16* attn_out = h;

    ln_kernel<<<NTOK, 256, 0, stream>>>(x, ln_w, ln_b, h);
    cast_kernel<<<(3 * D * D) / 1024, 256, 0, stream>>>(qkv_w, wq, 3 * D * D);
    cast_kernel<<<(D * D) / 1024, 256, 0, stream>>>(out_w, wo, D * D);

    {
        dim3 grid(3 * D / 128, NTOK / 128);
        gemm_bf16<u16, false><<<grid, 256, 0, stream>>>(h, wq, qkv_b, nullptr, qkv,
                                                        NTOK, 3 * D, D);
    }

    knorm_kernel<<<NTOK * NH / 4, 256, 0, stream>>>(qkv);

    mha_kernel<<<BATCH * NH * (SEQ / 128), 256, 0, stream>>>(qkv, attn_out);

    {
        dim3 grid(D / 128, NTOK / 128);
        gemm_bf16<float, true><<<grid, 256, 0, stream>>>(attn_out, wo, out_b, x, y,
                                                         NTOK, D, D);
    }
}

// Round 7
// 312.278 us; speedup vs baseline: 26.4726x; 1.0892x over previous
//
#include <hip/hip_runtime.h>
#include <math.h>

// Problem constants
constexpr int D     = 1024;
constexpr int NH    = 16;
constexpr int HD    = 64;
constexpr int SEQ   = 2048;
constexpr int BATCH = 4;
constexpr int NTOK  = BATCH * SEQ;   // 8192 rows

typedef short s16x8 __attribute__((ext_vector_type(8)));
typedef short s16x4 __attribute__((ext_vector_type(4)));
typedef float f32x4 __attribute__((ext_vector_type(4)));
typedef unsigned short u16;
typedef unsigned int   u32;

#if __has_builtin(__builtin_amdgcn_exp2f)
#define EXP2(x) __builtin_amdgcn_exp2f(x)
#else
#define EXP2(x) exp2f(x)
#endif

__device__ __forceinline__ short f2bf(float f) {
    unsigned u = __float_as_uint(f);
    unsigned r = (u + 0x7FFFu + ((u >> 16) & 1u)) >> 16;   // RNE
    return (short)r;
}
__device__ __forceinline__ float bf2f(u16 s) {
    return __uint_as_float(((unsigned)s) << 16);
}

// pack hi16(f1)|hi16(f0) -> one u32 (lo = f0) via v_perm_b32
__device__ __forceinline__ u32 pack_bf16_pair(float f0, float f1) {
    u32 a = __float_as_uint(f1) + 0x8000u;   // round half up
    u32 b = __float_as_uint(f0) + 0x8000u;
    return __builtin_amdgcn_perm(a, b, 0x07060302u);
}

__device__ __forceinline__ void async_lds16(const void* g, void* l) {
    __builtin_amdgcn_global_load_lds(
        (const __attribute__((address_space(1))) unsigned int*)g,
        (__attribute__((address_space(3))) unsigned int*)l, 16, 0, 0);
}

// ---------------------------------------------------------------------------
// Reductions (wave = 64)
// ---------------------------------------------------------------------------
__device__ __forceinline__ float block_reduce_sum(float v, float* red) {
    int lane = threadIdx.x & 63, wid = threadIdx.x >> 6;
    #pragma unroll
    for (int off = 32; off > 0; off >>= 1) v += __shfl_down(v, off, 64);
    if (lane == 0) red[wid] = v;
    __syncthreads();
    float r = red[0] + red[1] + red[2] + red[3];
    __syncthreads();
    return r;
}

// ---------------------------------------------------------------------------
// 1) LayerNorm (fp32 math) -> bf16 h
// ---------------------------------------------------------------------------
__global__ __launch_bounds__(256) void ln_kernel(const float* __restrict__ x,
                                                 const float* __restrict__ w,
                                                 const float* __restrict__ b,
                                                 u16* __restrict__ h) {
    __shared__ float red[4];
    int row = blockIdx.x;
    const float* xr = x + (size_t)row * D;
    int t = threadIdx.x;
    float v[4];
    float s = 0.f;
    #pragma unroll
    for (int i = 0; i < 4; i++) { v[i] = xr[t + 256 * i]; s += v[i]; }
    float mean = block_reduce_sum(s, red) * (1.0f / 1024.0f);
    float ss = 0.f;
    #pragma unroll
    for (int i = 0; i < 4; i++) { float d = v[i] - mean; ss += d * d; }
    float var = block_reduce_sum(ss, red) * (1.0f / 1024.0f);
    float rstd = rsqrtf(var + 1e-5f);
    u16* hr = h + (size_t)row * D;
    #pragma unroll
    for (int i = 0; i < 4; i++) {
        int c = t + 256 * i;
        hr[c] = (u16)f2bf((v[i] - mean) * rstd * w[c] + b[c]);
    }
}

// ---------------------------------------------------------------------------
// 1b) fp32 -> bf16 cast (weights); n divisible by 1024
// ---------------------------------------------------------------------------
__global__ __launch_bounds__(256) void cast_kernel(const float* __restrict__ in,
                                                   u16* __restrict__ out, int n) {
    int i = (blockIdx.x * 256 + threadIdx.x) * 4;
    if (i >= n) return;
    float4 f = *(const float4*)(in + i);
    s16x4 o4;
    o4[0] = f2bf(f.x); o4[1] = f2bf(f.y); o4[2] = f2bf(f.z); o4[3] = f2bf(f.w);
    *(s16x4*)(out + i) = o4;
}

// ---------------------------------------------------------------------------
// 2) bf16 MFMA GEMM (m97 structure): C[M,N] = A[M,K] @ B[N,K]^T + bias (+R)
// ---------------------------------------------------------------------------
template <typename OutT, bool RES>
__global__ __launch_bounds__(256) void gemm_bf16(const u16* __restrict__ A,
                                                 const u16* __restrict__ B,
                                                 const float* __restrict__ bias,
                                                 const float* __restrict__ R,
                                                 OutT* __restrict__ C,
                                                 int M, int N, int K) {
    __shared__ u16 As[128 * 32];
    __shared__ u16 Bs[128 * 32];
    int tid = threadIdx.x, wave = tid >> 6, lane = tid & 63;
    int quad = lane >> 4, l16 = lane & 15;
    int wm = (wave & 1) * 64, wn = (wave >> 1) * 64;
    int rowBase = blockIdx.y * 128, colBase = blockIdx.x * 128;

    int srow = lane >> 2;
    int sk8  = (lane & 3) * 8;

    f32x4 acc[4][4];
    #pragma unroll
    for (int i = 0; i < 4; i++)
        #pragma unroll
        for (int j = 0; j < 4; j++)
            acc[i][j] = (f32x4){0.f, 0.f, 0.f, 0.f};

    for (int k0 = 0; k0 < K; k0 += 32) {
        __syncthreads();
        #pragma unroll
        for (int i = 0; i < 2; i++) {
            int r = wave * 32 + i * 16;
            const u16* ga = A + (size_t)(rowBase + r + srow) * K + k0 + sk8;
            async_lds16(ga, &As[r * 32]);
            const u16* gb = B + (size_t)(colBase + r + srow) * K + k0 + sk8;
            async_lds16(gb, &Bs[r * 32]);
        }
        __syncthreads();

        s16x8 af[4], bfr[4];
        #pragma unroll
        for (int t = 0; t < 4; t++) {
            af[t]  = *(const s16x8*)&As[(wm + t * 16 + l16) * 32 + quad * 8];
            bfr[t] = *(const s16x8*)&Bs[(wn + t * 16 + l16) * 32 + quad * 8];
        }
        #pragma unroll
        for (int mt = 0; mt < 4; mt++)
            #pragma unroll
            for (int nt = 0; nt < 4; nt++)
                acc[mt][nt] = __builtin_amdgcn_mfma_f32_16x16x32_bf16(
                    af[mt], bfr[nt], acc[mt][nt], 0, 0, 0);
    }

    #pragma unroll
    for (int mt = 0; mt < 4; mt++) {
        #pragma unroll
        for (int nt = 0; nt < 4; nt++) {
            int gm0 = rowBase + wm + mt * 16 + quad * 4;
            int gn  = colBase + wn + nt * 16 + l16;
            float bv = bias[gn];
            #pragma unroll
            for (int r = 0; r < 4; r++) {
                int gm = gm0 + r;
                float val = acc[mt][nt][r] + bv;
                if (RES) val += R[(size_t)gm * N + gn];
                if constexpr (sizeof(OutT) == 2)
                    C[(size_t)gm * N + gn] = (OutT)f2bf(val);
                else
                    C[(size_t)gm * N + gn] = val;
            }
        }
    }
}

// ---------------------------------------------------------------------------
// 3) k L2 normalization in-place on bf16 qkv (q is normalized inside mha)
// ---------------------------------------------------------------------------
__global__ __launch_bounds__(256) void knorm_kernel(u16* __restrict__ qkv) {
    int gw = (blockIdx.x * 256 + threadIdx.x) >> 6;
    int lane = threadIdx.x & 63;
    int row = gw / NH, hh = gw - row * NH;
    u16* kp = qkv + (size_t)row * 3072 + 1024 + hh * 64;

    float kv = bf2f(kp[lane]);
    float s = kv * kv;
    #pragma unroll
    for (int off = 32; off > 0; off >>= 1) s += __shfl_down(s, off, 64);
    s = __shfl(s, 0, 64);
    kp[lane] = (u16)f2bf(kv / fmaxf(sqrtf(s), 1e-12f));
}

// ---------------------------------------------------------------------------
// 4) MFMA flash attention v5.
//    Block = one (b,h) x 256 q-rows; 4 waves x 64 q-rows (4 row-tiles of 16).
//    Grid = 512. K/V staging + frag reads amortize over 2x the MFMA work.
//    * Ks: unpadded [64][64] with 16B-chunk XOR swizzle
//      (physical chunk = logical ^ (row&7)) -> conflict-free b128 write+read.
//    * Vt: transposed, row stride 68 u16 -> V-transpose write 4-way (was
//      8-way), b64 frag reads at the 4-phase minimum, 8B-aligned.
//    * S^T = mfma(K, SCL*Q, C=-SCL); p = exp2(s); P stays in registers and
//      feeds PV directly via contraction-index permutation (R6 scheme).
// ---------------------------------------------------------------------------
__global__ __launch_bounds__(256, 2) void mha_kernel(const u16* __restrict__ qkv,
                                                     u16* __restrict__ out) {
    __shared__ u16 Ks[64 * 64];       // swizzled [row][8 chunks of 8 u16]
    constexpr int VS = 68;            // Vt row stride (u16): 136 B
    __shared__ u16 Vt[64 * VS];       // V tile [d][key] (transposed)

    int bh = blockIdx.x >> 3;         // SEQ/256 = 8 q-tiles
    int qt = blockIdx.x & 7;
    int b  = bh >> 4, h = bh & 15;
    int tid = threadIdx.x;
    int wave = tid >> 6, lane = tid & 63;
    int quad = lane >> 4, l16 = lane & 15;

    const size_t rs = 3072;
    constexpr float SCL = 11.5415605f;   // 8 * log2(e)

    // --- Q frags: load raw q, L2-normalize in-register, fold SCL ---
    s16x8 aq[4][2];
    #pragma unroll
    for (int rt = 0; rt < 4; rt++) {
        const u16* qb = qkv + ((size_t)(b * SEQ) + qt * 256 + wave * 64 + rt * 16 + l16) * rs + h * 64;
        s16x8 r0 = *(const s16x8*)(qb + quad * 8);
        s16x8 r1 = *(const s16x8*)(qb + 32 + quad * 8);
        float f0[8], f1[8], ss = 0.f;
        #pragma unroll
        for (int i = 0; i < 8; i++) { f0[i] = bf2f((u16)r0[i]); ss = fmaf(f0[i], f0[i], ss); }
        #pragma unroll
        for (int i = 0; i < 8; i++) { f1[i] = bf2f((u16)r1[i]); ss = fmaf(f1[i], f1[i], ss); }
        ss += __shfl_xor(ss, 16, 64);
        ss += __shfl_xor(ss, 32, 64);
        float inv = SCL / fmaxf(sqrtf(ss), 1e-12f);
        #pragma unroll
        for (int i = 0; i < 8; i++) {
            aq[rt][0][i] = f2bf(f0[i] * inv);
            aq[rt][1][i] = f2bf(f1[i] * inv);
        }
    }

    const f32x4 cinit = {-SCL, -SCL, -SCL, -SCL};
    f32x4 o2[4][4];   // O^T frags: lane holds d=ht*16+quad*4+r, qrow=l16
    #pragma unroll
    for (int rt = 0; rt < 4; rt++)
        #pragma unroll
        for (int ht = 0; ht < 4; ht++) o2[rt][ht] = (f32x4){0.f, 0.f, 0.f, 0.f};
    float lsum[4] = {0.f, 0.f, 0.f, 0.f};

    // staging assignments
    int skey = tid >> 2, c4 = tid & 3;            // K: row skey, chunks 2c4,2c4+1
    int ksw  = skey & 7;                          // K swizzle key
    int vp2 = tid >> 3, dc = (tid & 7) * 8;       // V: key pair (2vp2,2vp2+1)
    const u16* kglob  = qkv + ((size_t)(b * SEQ) + skey) * rs + 1024 + h * 64 + c4 * 16;
    const u16* vglob0 = qkv + ((size_t)(b * SEQ) + 2 * vp2) * rs + 2048 + h * 64 + dc;
    u16* kdst0 = &Ks[skey * 64 + ((2 * c4)     ^ ksw) * 8];
    u16* kdst1 = &Ks[skey * 64 + ((2 * c4 + 1) ^ ksw) * 8];
    u32* vt32 = (u32*)&Vt[0];

    // prefetch tile 0
    s16x8 kr0 = ((const s16x8*)kglob)[0];
    s16x8 kr1 = ((const s16x8*)kglob)[1];
    s16x8 vr0 = *(const s16x8*)(vglob0);
    s16x8 vr1 = *(const s16x8*)(vglob0 + rs);

    int swz = l16 & 7;   // read-side swizzle key (row & 7 = l16 & 7)

    for (int kb = 0; kb < SEQ / 64; kb++) {
        __syncthreads();   // previous tile's LDS reads done
        *(s16x8*)kdst0 = kr0;
        *(s16x8*)kdst1 = kr1;
        #pragma unroll
        for (int i = 0; i < 8; i++) {
            u32 pk = (u32)(u16)vr0[i] | ((u32)(u16)vr1[i] << 16);
            vt32[(dc + i) * (VS / 2) + vp2] = pk;
        }
        __syncthreads();

        // prefetch next tile into regs (overlaps compute)
        if (kb < SEQ / 64 - 1) {
            const u16* kp = kglob + (size_t)(kb + 1) * 64 * rs;
            const u16* vp = vglob0 + (size_t)(kb + 1) * 64 * rs;
            kr0 = ((const s16x8*)kp)[0];
            kr1 = ((const s16x8*)kp)[1];
            vr0 = *(const s16x8*)(vp);
            vr1 = *(const s16x8*)(vp + rs);
        }

        // --- S^T = K.(SCL*Q)^T - SCL ; p = exp2(s); packed P in regs ---
        s16x4 pfr[4][4];      // [rt][t]: P[qrow=l16][key=t*16+quad*4+{0..3}]
        float sum16[4] = {0.f, 0.f, 0.f, 0.f};
        #pragma unroll
        for (int t = 0; t < 4; t++) {
            const u16* krow = &Ks[(t * 16 + l16) * 64];
            s16x8 bk0 = *(const s16x8*)(krow + ((0 + quad) ^ swz) * 8);
            s16x8 bk1 = *(const s16x8*)(krow + ((4 + quad) ^ swz) * 8);
            #pragma unroll
            for (int rt = 0; rt < 4; rt++) {
                f32x4 s = cinit;
                s = __builtin_amdgcn_mfma_f32_16x16x32_bf16(bk0, aq[rt][0], s, 0, 0, 0);
                s = __builtin_amdgcn_mfma_f32_16x16x32_bf16(bk1, aq[rt][1], s, 0, 0, 0);
                float p0 = EXP2(s[0]);
                float p1 = EXP2(s[1]);
                float p2 = EXP2(s[2]);
                float p3 = EXP2(s[3]);
                sum16[rt] += (p0 + p1) + (p2 + p3);
                uint2 pk2;
                pk2.x = pack_bf16_pair(p0, p1);
                pk2.y = pack_bf16_pair(p2, p3);
                pfr[rt][t] = __builtin_bit_cast(s16x4, pk2);
            }
        }
        #pragma unroll
        for (int rt = 0; rt < 4; rt++) {
            float s16v = sum16[rt];
            s16v += __shfl_xor(s16v, 16, 64);
            s16v += __shfl_xor(s16v, 32, 64);
            lsum[rt] += s16v;
        }

        // --- O^T += V^T.P^T with permuted key order (pairs (0,1),(2,3)) ---
        #pragma unroll
        for (int pr = 0; pr < 2; pr++) {
            int tA = pr * 2, tB = pr * 2 + 1;
            #pragma unroll
            for (int ht = 0; ht < 4; ht++) {
                const u16* vrow = &Vt[(ht * 16 + l16) * VS];
                s16x4 va = *(const s16x4*)(vrow + tA * 16 + quad * 4);
                s16x4 vb = *(const s16x4*)(vrow + tB * 16 + quad * 4);
                s16x8 vfr = __builtin_shufflevector(va, vb, 0, 1, 2, 3, 4, 5, 6, 7);
                #pragma unroll
                for (int rt = 0; rt < 4; rt++) {
                    s16x8 bp = __builtin_shufflevector(pfr[rt][tA], pfr[rt][tB],
                                                       0, 1, 2, 3, 4, 5, 6, 7);
                    o2[rt][ht] = __builtin_amdgcn_mfma_f32_16x16x32_bf16(
                        vfr, bp, o2[rt][ht], 0, 0, 0);
                }
            }
        }
    }

    // --- epilogue: lane owns qrow=l16 (per rt), d = ht*16+quad*4+r ---
    #pragma unroll
    for (int rt = 0; rt < 4; rt++) {
        float inv = 1.0f / lsum[rt];
        int orow = b * SEQ + qt * 256 + wave * 64 + rt * 16 + l16;
        u16* op = out + (size_t)orow * D + h * 64 + quad * 4;
        #pragma unroll
        for (int ht = 0; ht < 4; ht++) {
            f32x4 v = o2[rt][ht];
            u32 lo = pack_bf16_pair(v[0] * inv, v[1] * inv);
            u32 hi = pack_bf16_pair(v[2] * inv, v[3] * inv);
            uint2 pk = {lo, hi};
            *(uint2*)(op + ht * 16) = pk;
        }
    }
}

// ---------------------------------------------------------------------------
// launch
// ---------------------------------------------------------------------------
extern "C" void kernel_launch(void* const* d_in, const int* in_sizes, int n_in,
                              void* d_out, int out_size, void* d_ws, size_t ws_size,
                              hipStream_t stream) {
    const float* x     = (const float*)d_in[0];
    const float* ln_w  = (const float*)d_in[1];
    const float* ln_b  = (const float*)d_in[2];
    const float* qkv_w = (const float*)d_in[3];
    const float* qkv_b = (const float*)d_in[4];
    const float* out_w = (const float*)d_in[5];
    const float* out_b = (const float*)d_in[6];
    float* y = (float*)d_out;

    // workspace carve-up: qkv 48MB | h 16MB | wq 6MB | wo 2MB
    char* ws = (char*)d_ws;
    u16* qkv = (u16*)ws;
    u16* h   = (u16*)(ws + (size_t)48 * 1024 * 1024);
    u16* wq  = (u16*)(ws + (size_t)64 * 1024 * 1024);
    u16* wo  = (u16*)(ws + (size_t)70 * 1024 * 1024);
    u16* attn_out = h;

    ln_kernel<<<NTOK, 256, 0, stream>>>(x, ln_w, ln_b, h);
    cast_kernel<<<(3 * D * D) / 1024, 256, 0, stream>>>(qkv_w, wq, 3 * D * D);
    cast_kernel<<<(D * D) / 1024, 256, 0, stream>>>(out_w, wo, D * D);

    {
        dim3 grid(3 * D / 128, NTOK / 128);
        gemm_bf16<u16, false><<<grid, 256, 0, stream>>>(h, wq, qkv_b, nullptr, qkv,
                                                        NTOK, 3 * D, D);
    }

    knorm_kernel<<<NTOK * NH / 4, 256, 0, stream>>>(qkv);

    mha_kernel<<<BATCH * NH * (SEQ / 256), 256, 0, stream>>>(qkv, attn_out);

    {
        dim3 grid(D / 128, NTOK / 128);
        gemm_bf16<float, true><<<grid, 256, 0, stream>>>(attn_out, wo, out_b, x, y,
                                                         NTOK, D, D);
    }
}

// Round 8
// 284.868 us; speedup vs baseline: 29.0199x; 1.0962x over previous
//
#include <hip/hip_runtime.h>
#include <math.h>

// Problem constants
constexpr int D     = 1024;
constexpr int NH    = 16;
constexpr int HD    = 64;
constexpr int SEQ   = 2048;
constexpr int BATCH = 4;
constexpr int NTOK  = BATCH * SEQ;   // 8192 rows

typedef short s16x8 __attribute__((ext_vector_type(8)));
typedef short s16x4 __attribute__((ext_vector_type(4)));
typedef float f32x4 __attribute__((ext_vector_type(4)));
typedef unsigned short u16;
typedef unsigned int   u32;

#if __has_builtin(__builtin_amdgcn_exp2f)
#define EXP2(x) __builtin_amdgcn_exp2f(x)
#else
#define EXP2(x) exp2f(x)
#endif

__device__ __forceinline__ short f2bf(float f) {
    unsigned u = __float_as_uint(f);
    unsigned r = (u + 0x7FFFu + ((u >> 16) & 1u)) >> 16;   // RNE
    return (short)r;
}
__device__ __forceinline__ float bf2f(u16 s) {
    return __uint_as_float(((unsigned)s) << 16);
}

// pack hi16(f1)|hi16(f0) -> one u32 (lo = f0) via v_perm_b32
__device__ __forceinline__ u32 pack_bf16_pair(float f0, float f1) {
    u32 a = __float_as_uint(f1) + 0x8000u;   // round half up
    u32 b = __float_as_uint(f0) + 0x8000u;
    return __builtin_amdgcn_perm(a, b, 0x07060302u);
}

__device__ __forceinline__ void async_lds16(const void* g, void* l) {
    __builtin_amdgcn_global_load_lds(
        (const __attribute__((address_space(1))) unsigned int*)g,
        (__attribute__((address_space(3))) unsigned int*)l, 16, 0, 0);
}

// ---------------------------------------------------------------------------
// Reductions (wave = 64)
// ---------------------------------------------------------------------------
__device__ __forceinline__ float block_reduce_sum(float v, float* red) {
    int lane = threadIdx.x & 63, wid = threadIdx.x >> 6;
    #pragma unroll
    for (int off = 32; off > 0; off >>= 1) v += __shfl_down(v, off, 64);
    if (lane == 0) red[wid] = v;
    __syncthreads();
    float r = red[0] + red[1] + red[2] + red[3];
    __syncthreads();
    return r;
}

// ---------------------------------------------------------------------------
// 1) LayerNorm (fp32 math) -> bf16 h
// ---------------------------------------------------------------------------
__global__ __launch_bounds__(256) void ln_kernel(const float* __restrict__ x,
                                                 const float* __restrict__ w,
                                                 const float* __restrict__ b,
                                                 u16* __restrict__ h) {
    __shared__ float red[4];
    int row = blockIdx.x;
    const float* xr = x + (size_t)row * D;
    int t = threadIdx.x;
    float v[4];
    float s = 0.f;
    #pragma unroll
    for (int i = 0; i < 4; i++) { v[i] = xr[t + 256 * i]; s += v[i]; }
    float mean = block_reduce_sum(s, red) * (1.0f / 1024.0f);
    float ss = 0.f;
    #pragma unroll
    for (int i = 0; i < 4; i++) { float d = v[i] - mean; ss += d * d; }
    float var = block_reduce_sum(ss, red) * (1.0f / 1024.0f);
    float rstd = rsqrtf(var + 1e-5f);
    u16* hr = h + (size_t)row * D;
    #pragma unroll
    for (int i = 0; i < 4; i++) {
        int c = t + 256 * i;
        hr[c] = (u16)f2bf((v[i] - mean) * rstd * w[c] + b[c]);
    }
}

// ---------------------------------------------------------------------------
// 1b) fp32 -> bf16 cast (weights); n divisible by 1024
// ---------------------------------------------------------------------------
__global__ __launch_bounds__(256) void cast_kernel(const float* __restrict__ in,
                                                   u16* __restrict__ out, int n) {
    int i = (blockIdx.x * 256 + threadIdx.x) * 4;
    if (i >= n) return;
    float4 f = *(const float4*)(in + i);
    s16x4 o4;
    o4[0] = f2bf(f.x); o4[1] = f2bf(f.y); o4[2] = f2bf(f.z); o4[3] = f2bf(f.w);
    *(s16x4*)(out + i) = o4;
}

// ---------------------------------------------------------------------------
// 2) bf16 MFMA GEMM (m97 structure): C[M,N] = A[M,K] @ B[N,K]^T + bias (+R)
//    NORMK: L2-normalize each 64-col head segment for cols in [1024,2048)
//    (fused F.normalize for k; each wave's 64-col span == one head).
// ---------------------------------------------------------------------------
template <typename OutT, bool RES, bool NORMK>
__global__ __launch_bounds__(256) void gemm_bf16(const u16* __restrict__ A,
                                                 const u16* __restrict__ B,
                                                 const float* __restrict__ bias,
                                                 const float* __restrict__ R,
                                                 OutT* __restrict__ C,
                                                 int M, int N, int K) {
    __shared__ u16 As[128 * 32];
    __shared__ u16 Bs[128 * 32];
    int tid = threadIdx.x, wave = tid >> 6, lane = tid & 63;
    int quad = lane >> 4, l16 = lane & 15;
    int wm = (wave & 1) * 64, wn = (wave >> 1) * 64;
    int rowBase = blockIdx.y * 128, colBase = blockIdx.x * 128;

    int srow = lane >> 2;
    int sk8  = (lane & 3) * 8;

    f32x4 acc[4][4];
    #pragma unroll
    for (int i = 0; i < 4; i++)
        #pragma unroll
        for (int j = 0; j < 4; j++)
            acc[i][j] = (f32x4){0.f, 0.f, 0.f, 0.f};

    for (int k0 = 0; k0 < K; k0 += 32) {
        __syncthreads();
        #pragma unroll
        for (int i = 0; i < 2; i++) {
            int r = wave * 32 + i * 16;
            const u16* ga = A + (size_t)(rowBase + r + srow) * K + k0 + sk8;
            async_lds16(ga, &As[r * 32]);
            const u16* gb = B + (size_t)(colBase + r + srow) * K + k0 + sk8;
            async_lds16(gb, &Bs[r * 32]);
        }
        __syncthreads();

        s16x8 af[4], bfr[4];
        #pragma unroll
        for (int t = 0; t < 4; t++) {
            af[t]  = *(const s16x8*)&As[(wm + t * 16 + l16) * 32 + quad * 8];
            bfr[t] = *(const s16x8*)&Bs[(wn + t * 16 + l16) * 32 + quad * 8];
        }
        #pragma unroll
        for (int mt = 0; mt < 4; mt++)
            #pragma unroll
            for (int nt = 0; nt < 4; nt++)
                acc[mt][nt] = __builtin_amdgcn_mfma_f32_16x16x32_bf16(
                    af[mt], bfr[nt], acc[mt][nt], 0, 0, 0);
    }

    // wave-uniform: does this wave's 64-col span hold k values?
    bool normk = NORMK && (colBase + wn) >= 1024 && (colBase + wn) < 2048;

    #pragma unroll
    for (int mt = 0; mt < 4; mt++) {
        float vals[4][4];   // [nt][r]
        #pragma unroll
        for (int nt = 0; nt < 4; nt++) {
            int gn = colBase + wn + nt * 16 + l16;
            float bv = bias[gn];
            #pragma unroll
            for (int r = 0; r < 4; r++) {
                float val = acc[mt][nt][r] + bv;
                if (RES) {
                    int gm = rowBase + wm + mt * 16 + quad * 4 + r;
                    val += R[(size_t)gm * N + gn];
                }
                vals[nt][r] = val;
            }
        }
        if (normk) {
            #pragma unroll
            for (int r = 0; r < 4; r++) {
                float ssq = 0.f;
                #pragma unroll
                for (int nt = 0; nt < 4; nt++) ssq = fmaf(vals[nt][r], vals[nt][r], ssq);
                ssq += __shfl_xor(ssq, 1, 64);
                ssq += __shfl_xor(ssq, 2, 64);
                ssq += __shfl_xor(ssq, 4, 64);
                ssq += __shfl_xor(ssq, 8, 64);
                float inv = 1.0f / fmaxf(sqrtf(ssq), 1e-12f);
                #pragma unroll
                for (int nt = 0; nt < 4; nt++) vals[nt][r] *= inv;
            }
        }
        #pragma unroll
        for (int nt = 0; nt < 4; nt++) {
            int gn = colBase + wn + nt * 16 + l16;
            int gm0 = rowBase + wm + mt * 16 + quad * 4;
            #pragma unroll
            for (int r = 0; r < 4; r++) {
                if constexpr (sizeof(OutT) == 2)
                    C[(size_t)(gm0 + r) * N + gn] = (OutT)f2bf(vals[nt][r]);
                else
                    C[(size_t)(gm0 + r) * N + gn] = vals[nt][r];
            }
        }
    }
}

// ---------------------------------------------------------------------------
// 4) MFMA flash attention v6.
//    Block = one (b,h) x 256 q-rows; 4 waves x 64 q-rows (4 row-tiles of 16).
//    Grid 512, XCD-swizzled: bh = blk & 63 -> all 8 q-tiles of one head land
//    on the same XCD (blk%8 invariant) -> K/V cached once per L2.
//    * Ks: [64][64] with 16B-chunk XOR swizzle -> conflict-free b128 r/w.
//    * Vt: transposed, stride 68 u16 -> 4-way write, clean b64 reads.
//    * S^T = mfma(K, SCL*Q, C=-SCL); p = exp2(s); P register-resident,
//      feeds PV via contraction-index permutation.
//    * lsum on the matrix pipe: all-ones A-frag sum tile (accumulates
//      across kb in its own C-frag) -- no VALU row sums.
//    k is pre-normalized by the QKV GEMM epilogue; q normalized here.
// ---------------------------------------------------------------------------
__global__ __launch_bounds__(256, 2) void mha_kernel(const u16* __restrict__ qkv,
                                                     u16* __restrict__ out) {
    __shared__ u16 Ks[64 * 64];       // swizzled [row][8 chunks of 8 u16]
    constexpr int VS = 68;            // Vt row stride (u16): 136 B
    __shared__ u16 Vt[64 * VS];       // V tile [d][key] (transposed)

    int bh = blockIdx.x & 63;         // XCD-locality swizzle
    int qt = blockIdx.x >> 6;         // 8 q-tiles of 256 rows
    int b  = bh >> 4, h = bh & 15;
    int tid = threadIdx.x;
    int wave = tid >> 6, lane = tid & 63;
    int quad = lane >> 4, l16 = lane & 15;

    const size_t rs = 3072;
    constexpr float SCL = 11.5415605f;   // 8 * log2(e)

    // --- Q frags: load raw q, L2-normalize in-register, fold SCL ---
    s16x8 aq[4][2];
    #pragma unroll
    for (int rt = 0; rt < 4; rt++) {
        const u16* qb = qkv + ((size_t)(b * SEQ) + qt * 256 + wave * 64 + rt * 16 + l16) * rs + h * 64;
        s16x8 r0 = *(const s16x8*)(qb + quad * 8);
        s16x8 r1 = *(const s16x8*)(qb + 32 + quad * 8);
        float f0[8], f1[8], ss = 0.f;
        #pragma unroll
        for (int i = 0; i < 8; i++) { f0[i] = bf2f((u16)r0[i]); ss = fmaf(f0[i], f0[i], ss); }
        #pragma unroll
        for (int i = 0; i < 8; i++) { f1[i] = bf2f((u16)r1[i]); ss = fmaf(f1[i], f1[i], ss); }
        ss += __shfl_xor(ss, 16, 64);
        ss += __shfl_xor(ss, 32, 64);
        float inv = SCL / fmaxf(sqrtf(ss), 1e-12f);
        #pragma unroll
        for (int i = 0; i < 8; i++) {
            aq[rt][0][i] = f2bf(f0[i] * inv);
            aq[rt][1][i] = f2bf(f1[i] * inv);
        }
    }

    const f32x4 cinit = {-SCL, -SCL, -SCL, -SCL};
    f32x4 o2[4][4];    // O^T frags: lane holds d=ht*16+quad*4+r, qrow=l16
    f32x4 osum[4];     // ones-tile accumulators: lsum[rt] = osum[rt][0]
    #pragma unroll
    for (int rt = 0; rt < 4; rt++) {
        #pragma unroll
        for (int ht = 0; ht < 4; ht++) o2[rt][ht] = (f32x4){0.f, 0.f, 0.f, 0.f};
        osum[rt] = (f32x4){0.f, 0.f, 0.f, 0.f};
    }
    s16x8 ones;
    #pragma unroll
    for (int i = 0; i < 8; i++) ones[i] = (short)0x3F80;   // bf16 1.0

    // staging assignments
    int skey = tid >> 2, c4 = tid & 3;            // K: row skey, chunks 2c4,2c4+1
    int ksw  = skey & 7;                          // K swizzle key
    int vp2 = tid >> 3, dc = (tid & 7) * 8;       // V: key pair (2vp2,2vp2+1)
    const u16* kglob  = qkv + ((size_t)(b * SEQ) + skey) * rs + 1024 + h * 64 + c4 * 16;
    const u16* vglob0 = qkv + ((size_t)(b * SEQ) + 2 * vp2) * rs + 2048 + h * 64 + dc;
    u16* kdst0 = &Ks[skey * 64 + ((2 * c4)     ^ ksw) * 8];
    u16* kdst1 = &Ks[skey * 64 + ((2 * c4 + 1) ^ ksw) * 8];
    u32* vt32 = (u32*)&Vt[0];

    // prefetch tile 0
    s16x8 kr0 = ((const s16x8*)kglob)[0];
    s16x8 kr1 = ((const s16x8*)kglob)[1];
    s16x8 vr0 = *(const s16x8*)(vglob0);
    s16x8 vr1 = *(const s16x8*)(vglob0 + rs);

    int swz = l16 & 7;   // read-side swizzle key (row & 7 = l16 & 7)

    for (int kb = 0; kb < SEQ / 64; kb++) {
        __syncthreads();   // previous tile's LDS reads done
        *(s16x8*)kdst0 = kr0;
        *(s16x8*)kdst1 = kr1;
        #pragma unroll
        for (int i = 0; i < 8; i++) {
            u32 pk = (u32)(u16)vr0[i] | ((u32)(u16)vr1[i] << 16);
            vt32[(dc + i) * (VS / 2) + vp2] = pk;
        }
        __syncthreads();

        // prefetch next tile into regs (overlaps compute)
        if (kb < SEQ / 64 - 1) {
            const u16* kp = kglob + (size_t)(kb + 1) * 64 * rs;
            const u16* vp = vglob0 + (size_t)(kb + 1) * 64 * rs;
            kr0 = ((const s16x8*)kp)[0];
            kr1 = ((const s16x8*)kp)[1];
            vr0 = *(const s16x8*)(vp);
            vr1 = *(const s16x8*)(vp + rs);
        }

        // --- S^T = K.(SCL*Q)^T - SCL ; p = exp2(s); packed P in regs ---
        s16x4 pfr[4][4];      // [rt][t]: P[qrow=l16][key=t*16+quad*4+{0..3}]
        #pragma unroll
        for (int t = 0; t < 4; t++) {
            const u16* krow = &Ks[(t * 16 + l16) * 64];
            s16x8 bk0 = *(const s16x8*)(krow + ((0 + quad) ^ swz) * 8);
            s16x8 bk1 = *(const s16x8*)(krow + ((4 + quad) ^ swz) * 8);
            #pragma unroll
            for (int rt = 0; rt < 4; rt++) {
                f32x4 s = cinit;
                s = __builtin_amdgcn_mfma_f32_16x16x32_bf16(bk0, aq[rt][0], s, 0, 0, 0);
                s = __builtin_amdgcn_mfma_f32_16x16x32_bf16(bk1, aq[rt][1], s, 0, 0, 0);
                uint2 pk2;
                pk2.x = pack_bf16_pair(EXP2(s[0]), EXP2(s[1]));
                pk2.y = pack_bf16_pair(EXP2(s[2]), EXP2(s[3]));
                pfr[rt][t] = __builtin_bit_cast(s16x4, pk2);
            }
        }

        // --- O^T += V^T.P^T (+ ones sum tile), permuted key order ---
        #pragma unroll
        for (int pr = 0; pr < 2; pr++) {
            int tA = pr * 2, tB = pr * 2 + 1;
            s16x8 bp[4];
            #pragma unroll
            for (int rt = 0; rt < 4; rt++)
                bp[rt] = __builtin_shufflevector(pfr[rt][tA], pfr[rt][tB],
                                                 0, 1, 2, 3, 4, 5, 6, 7);
            #pragma unroll
            for (int ht = 0; ht < 4; ht++) {
                const u16* vrow = &Vt[(ht * 16 + l16) * VS];
                s16x4 va = *(const s16x4*)(vrow + tA * 16 + quad * 4);
                s16x4 vb = *(const s16x4*)(vrow + tB * 16 + quad * 4);
                s16x8 vfr = __builtin_shufflevector(va, vb, 0, 1, 2, 3, 4, 5, 6, 7);
                #pragma unroll
                for (int rt = 0; rt < 4; rt++)
                    o2[rt][ht] = __builtin_amdgcn_mfma_f32_16x16x32_bf16(
                        vfr, bp[rt], o2[rt][ht], 0, 0, 0);
            }
            #pragma unroll
            for (int rt = 0; rt < 4; rt++)
                osum[rt] = __builtin_amdgcn_mfma_f32_16x16x32_bf16(
                    ones, bp[rt], osum[rt], 0, 0, 0);
        }
    }

    // --- epilogue: lane owns qrow=l16 (per rt), d = ht*16+quad*4+r ---
    #pragma unroll
    for (int rt = 0; rt < 4; rt++) {
        float inv = 1.0f / osum[rt][0];
        int orow = b * SEQ + qt * 256 + wave * 64 + rt * 16 + l16;
        u16* op = out + (size_t)orow * D + h * 64 + quad * 4;
        #pragma unroll
        for (int ht = 0; ht < 4; ht++) {
            f32x4 v = o2[rt][ht];
            u32 lo = pack_bf16_pair(v[0] * inv, v[1] * inv);
            u32 hi = pack_bf16_pair(v[2] * inv, v[3] * inv);
            uint2 pk = {lo, hi};
            *(uint2*)(op + ht * 16) = pk;
        }
    }
}

// ---------------------------------------------------------------------------
// launch
// ---------------------------------------------------------------------------
extern "C" void kernel_launch(void* const* d_in, const int* in_sizes, int n_in,
                              void* d_out, int out_size, void* d_ws, size_t ws_size,
                              hipStream_t stream) {
    const float* x     = (const float*)d_in[0];
    const float* ln_w  = (const float*)d_in[1];
    const float* ln_b  = (const float*)d_in[2];
    const float* qkv_w = (const float*)d_in[3];
    const float* qkv_b = (const float*)d_in[4];
    const float* out_w = (const float*)d_in[5];
    const float* out_b = (const float*)d_in[6];
    float* y = (float*)d_out;

    // workspace carve-up: qkv 48MB | h 16MB | wq 6MB | wo 2MB
    char* ws = (char*)d_ws;
    u16* qkv = (u16*)ws;
    u16* h   = (u16*)(ws + (size_t)48 * 1024 * 1024);
    u16* wq  = (u16*)(ws + (size_t)64 * 1024 * 1024);
    u16* wo  = (u16*)(ws + (size_t)70 * 1024 * 1024);
    u16* attn_out = h;

    ln_kernel<<<NTOK, 256, 0, stream>>>(x, ln_w, ln_b, h);
    cast_kernel<<<(3 * D * D) / 1024, 256, 0, stream>>>(qkv_w, wq, 3 * D * D);
    cast_kernel<<<(D * D) / 1024, 256, 0, stream>>>(out_w, wo, D * D);

    // QKV GEMM with fused k L2-normalization in the epilogue
    {
        dim3 grid(3 * D / 128, NTOK / 128);
        gemm_bf16<u16, false, true><<<grid, 256, 0, stream>>>(h, wq, qkv_b, nullptr,
                                                              qkv, NTOK, 3 * D, D);
    }

    mha_kernel<<<BATCH * NH * (SEQ / 256), 256, 0, stream>>>(qkv, attn_out);

    {
        dim3 grid(D / 128, NTOK / 128);
        gemm_bf16<float, true, false><<<grid, 256, 0, stream>>>(attn_out, wo, out_b,
                                                                x, y, NTOK, D, D);
    }
}